// Round 4
// baseline (4154.425 us; speedup 1.0000x reference)
//
#include <hip/hip_runtime.h>
#include <math.h>

#define T_STEPS 64
#define BATCH   128
#define TBTOT   8192

typedef __attribute__((ext_vector_type(8))) short bf16x8;
typedef __attribute__((ext_vector_type(4))) float f32x4;

// ---------------- workspace layout (float offsets) ----------------
static const size_t OFF_CONV3  = 0;              // [8192][1568] f32 (phase 1)
static const size_t OFF_MWFHI  = 0;              // [4096*1024] bf16  (phase 2)
static const size_t OFF_MWFLO  = 2097152;        // [4096*1024] bf16
static const size_t OFF_EWFHI  = 4194304;        // [1024*256] bf16
static const size_t OFF_EWFLO  = 4325376;        // [1024*256] bf16
static const size_t OFF_HBMHI  = 4456448;        // [2][128][1024] bf16
static const size_t OFF_HBMLO  = 4587520;        // [2][128][1024] bf16
static const size_t OFF_HBEHI  = 4718592;        // [2][128][256] bf16
static const size_t OFF_HBELO  = 4734976;        // [2][128][256] bf16
static const size_t OFF_IMGH   = 12845056;       // [8192][256]
static const size_t OFF_LANGIN = 14942208;       // [8192][32]
static const size_t OFF_ENCXW  = 15204352;       // [8192][1024]
static const size_t OFF_ENCHS  = 23592960;       // [8192][256]
static const size_t OFF_LANGH  = 25690112;       // [8192][32]
static const size_t OFF_HIDDEN = 25952256;       // [8192][288]
static const size_t OFF_MEMXW  = 28311552;       // [8192][4096]
static const size_t OFF_MEMHS  = 61865984;       // [8192][1024]
static const size_t OFF_ENCBC  = 70582272;       // [1024]
static const size_t OFF_MEMBC  = 70583296;       // [4096]
static const size_t OFF_HEADW  = 70587392;       // [16][1024]
static const size_t OFF_HEADB  = 70603776;       // [16]
static const size_t OFF_BARS   = 70603792;       // 1280 uints (per-group barrier counters)

__device__ __forceinline__ float fast_sigm(float x) { return 1.0f / (1.0f + __expf(-x)); }
__device__ __forceinline__ float fast_tanh(float x) { return 2.0f / (1.0f + __expf(-2.0f * x)) - 1.0f; }

__device__ __forceinline__ short f32_to_bf16_rne(float x) {
    unsigned u = __float_as_uint(x);
    unsigned r = (u + 0x7fffu + ((u >> 16) & 1u)) >> 16;
    return (short)r;
}
__device__ __forceinline__ float bf16s_to_f32(short s) {
    return __uint_as_float(((unsigned)(unsigned short)s) << 16);
}

// -------- per-group hierarchical device-scope barrier --------
// Group region (160 uints): 8 sub-counters at [s*16] (own 64B lines), phase at [128].
// Monotone; prep zeroes each launch. round = 1,2,...; sub_target = blocks per sub.
__device__ __forceinline__ void gridbar2(unsigned* g, unsigned round,
                                         unsigned sub, unsigned sub_target) {
    __syncthreads();
    if (threadIdx.x == 0) {
        __threadfence();
        unsigned old = __hip_atomic_fetch_add(&g[sub * 16], 1u,
                                              __ATOMIC_RELEASE, __HIP_MEMORY_SCOPE_AGENT);
        if (old + 1u == sub_target * round) {
            __hip_atomic_fetch_add(&g[128], 1u,
                                   __ATOMIC_RELEASE, __HIP_MEMORY_SCOPE_AGENT);
        }
        while (__hip_atomic_load(&g[128], __ATOMIC_ACQUIRE,
                                 __HIP_MEMORY_SCOPE_AGENT) < 8u * round) {
            __builtin_amdgcn_s_sleep(1);
        }
    }
    __syncthreads();
}

// ---------------- prep ----------------
__global__ void prep_kernel(const float* __restrict__ enc_bih, const float* __restrict__ enc_bhh,
                            const float* __restrict__ mem_bih, const float* __restrict__ mem_bhh,
                            const float* __restrict__ actor_w, const float* __restrict__ actor_b,
                            const float* __restrict__ critic_w, const float* __restrict__ critic_b,
                            float* __restrict__ enc_bc, float* __restrict__ mem_bc,
                            float* __restrict__ head_w, float* __restrict__ head_b,
                            unsigned* __restrict__ bars) {
    int g = blockIdx.x * 256 + threadIdx.x;
    if (g < 1024)  enc_bc[g] = enc_bih[g] + enc_bhh[g];
    if (g < 4096)  mem_bc[g] = mem_bih[g] + mem_bhh[g];
    if (g < 16384) { int j = g >> 10, k = g & 1023; head_w[g] = (j < 15) ? actor_w[j * 1024 + k] : critic_w[k]; }
    if (g < 16)    head_b[g] = (g < 15) ? actor_b[g] : critic_b[0];
    if (g < 1280)  bars[g] = 0u;
}

// ---------------- split Whh into MFMA-fragment-ordered bf16 hi/lo ----------------
__global__ void split_frag_kernel(const float* __restrict__ W, short* __restrict__ hi,
                                  short* __restrict__ lo, int H) {
    size_t f = (size_t)blockIdx.x * 256 + threadIdx.x;
    size_t total = (size_t)4 * H * H;
    if (f >= total) return;
    int e    = (int)(f & 7);
    int lane = (int)((f >> 3) & 63);
    size_t rest = f >> 9;
    int nks = H >> 5;
    int ks  = (int)(rest % nks);
    int qjt = (int)(rest / nks);
    int njt = H >> 4;
    int qq = qjt / njt, jt = qjt - qq * njt;
    int n = qq * H + jt * 16 + (lane & 15);
    int k = ks * 32 + (lane >> 4) * 8 + e;
    float w = W[(size_t)n * H + k];
    short a = f32_to_bf16_rne(w);
    short b = f32_to_bf16_rne(w - bf16s_to_f32(a));
    hi[f] = a; lo[f] = b;
}

// ---------------- fused conv stack, one block per image ----------------
__global__ __launch_bounds__(256) void conv_kernel(const float* __restrict__ x,
        const float* __restrict__ w1, const float* __restrict__ b1,
        const float* __restrict__ w2, const float* __restrict__ b2,
        const float* __restrict__ w3, const float* __restrict__ b3,
        float* __restrict__ out) {
    __shared__ float arena[16384];
    const int t = threadIdx.x;
    const size_t img = blockIdx.x;

    float* s_out1 = arena;
    float* s_w1   = arena + 1936;
    float* s_b1   = arena + 3232;
    float* s_img  = arena + 3248;
    const float* xi = x + img * 9801;
    for (int i = t; i < 9801; i += 256) s_img[i] = xi[i] * (1.0f / 255.0f);
    for (int i = t; i < 1296; i += 256) s_w1[i] = w1[i];
    if (t < 16) s_b1[t] = b1[t];
    __syncthreads();

    if (t < 176) {
        int c = t / 11, i = t - c * 11;
        float accr[11];
        #pragma unroll
        for (int j = 0; j < 11; ++j) accr[j] = s_b1[c];
        for (int ky = 0; ky < 9; ++ky) {
            const float* irow = s_img + (i * 9 + ky) * 99;
            const float* wrow = s_w1 + c * 81 + ky * 9;
            for (int kx = 0; kx < 9; ++kx) {
                float wv = wrow[kx];
                #pragma unroll
                for (int j = 0; j < 11; ++j) accr[j] += wv * irow[j * 9 + kx];
            }
        }
        #pragma unroll
        for (int j = 0; j < 11; ++j) s_out1[c * 121 + i * 11 + j] = fmaxf(accr[j], 0.0f);
    }
    __syncthreads();

    float* s_w2   = arena + 1936;
    float* s_b2   = arena + 6544;
    float* s_out2 = arena + 13792;
    for (int i = t; i < 4608; i += 256) s_w2[i] = w2[i];
    if (t < 32) s_b2[t] = b2[t];
    __syncthreads();

    for (int rr = 0; rr < 2; ++rr) {
        int task = rr * 256 + t;
        if (task < 288) {
            int c = task / 9, i = task - c * 9;
            float accr[9];
            #pragma unroll
            for (int j = 0; j < 9; ++j) accr[j] = s_b2[c];
            for (int ic = 0; ic < 16; ++ic) {
                const float* ibase = s_out1 + ic * 121 + i * 11;
                const float* wbase = s_w2 + (c * 16 + ic) * 9;
                #pragma unroll
                for (int ky = 0; ky < 3; ++ky) {
                    const float* irow = ibase + ky * 11;
                    #pragma unroll
                    for (int kx = 0; kx < 3; ++kx) {
                        float wv = wbase[ky * 3 + kx];
                        #pragma unroll
                        for (int j = 0; j < 9; ++j) accr[j] += wv * irow[j + kx];
                    }
                }
            }
            #pragma unroll
            for (int j = 0; j < 9; ++j) s_out2[c * 81 + i * 9 + j] = fmaxf(accr[j], 0.0f);
        }
    }
    __syncthreads();

    float* s_w3   = arena;
    float* s_b3   = arena + 9216;
    float* s_out3 = arena + 9248;
    for (int i = t; i < 9216; i += 256) s_w3[i] = w3[i];
    if (t < 32) s_b3[t] = b3[t];
    __syncthreads();

    if (t < 224) {
        int c = t / 7, i = t - c * 7;
        float accr[7];
        #pragma unroll
        for (int j = 0; j < 7; ++j) accr[j] = s_b3[c];
        for (int ic = 0; ic < 32; ++ic) {
            const float* ibase = s_out2 + ic * 81 + i * 9;
            const float* wbase = s_w3 + (c * 32 + ic) * 9;
            #pragma unroll
            for (int ky = 0; ky < 3; ++ky) {
                const float* irow = ibase + ky * 9;
                #pragma unroll
                for (int kx = 0; kx < 3; ++kx) {
                    float wv = wbase[ky * 3 + kx];
                    #pragma unroll
                    for (int j = 0; j < 7; ++j) accr[j] += wv * irow[j + kx];
                }
            }
        }
        #pragma unroll
        for (int j = 0; j < 7; ++j) s_out3[c * 49 + i * 7 + j] = fmaxf(accr[j], 0.0f);
    }
    __syncthreads();
    float* og = out + img * 1568;
    for (int i = t; i < 1568; i += 256) og[i] = s_out3[i];
}

// ---------------- generic tiled GEMM ----------------
template <bool RELU>
__global__ __launch_bounds__(64) void gemm64(const float* __restrict__ A, const float* __restrict__ W,
                                             const float* __restrict__ bias, float* __restrict__ C,
                                             int M, int N, int K) {
    __shared__ float At[32][68];
    __shared__ float Wt[32][68];
    const int m0 = blockIdx.x * 64, n0 = blockIdx.y * 64;
    const int t = threadIdx.x;
    const int tx = t & 7, ty = t >> 3;
    float acc[8][8] = {};
    for (int kc = 0; kc < K; kc += 32) {
        #pragma unroll
        for (int i = 0; i < 8; ++i) {
            int e = t + i * 64;
            int row = e >> 3, c4 = (e & 7) * 4;
            float4 v = *(const float4*)&A[(size_t)(m0 + row) * K + kc + c4];
            At[c4 + 0][row] = v.x; At[c4 + 1][row] = v.y; At[c4 + 2][row] = v.z; At[c4 + 3][row] = v.w;
            int n = n0 + row;
            float4 wv = make_float4(0.f, 0.f, 0.f, 0.f);
            if (n < N) wv = *(const float4*)&W[(size_t)n * K + kc + c4];
            Wt[c4 + 0][row] = wv.x; Wt[c4 + 1][row] = wv.y; Wt[c4 + 2][row] = wv.z; Wt[c4 + 3][row] = wv.w;
        }
        __syncthreads();
        #pragma unroll
        for (int kk = 0; kk < 32; ++kk) {
            float4 a0 = *(const float4*)&At[kk][ty * 8];
            float4 a1 = *(const float4*)&At[kk][ty * 8 + 4];
            float4 b0 = *(const float4*)&Wt[kk][tx * 8];
            float4 b1 = *(const float4*)&Wt[kk][tx * 8 + 4];
            float a[8] = {a0.x, a0.y, a0.z, a0.w, a1.x, a1.y, a1.z, a1.w};
            float b[8] = {b0.x, b0.y, b0.z, b0.w, b1.x, b1.y, b1.z, b1.w};
            #pragma unroll
            for (int i = 0; i < 8; ++i)
                #pragma unroll
                for (int j = 0; j < 8; ++j) acc[i][j] += a[i] * b[j];
        }
        __syncthreads();
    }
    #pragma unroll
    for (int i = 0; i < 8; ++i) {
        int m = m0 + ty * 8 + i;
        #pragma unroll
        for (int j = 0; j < 8; ++j) {
            int n = n0 + tx * 8 + j;
            if (n < N) {
                float v = acc[i][j] + bias[n];
                if (RELU) v = fmaxf(v, 0.0f);
                C[(size_t)m * N + n] = v;
            }
        }
    }
}

// ---------------- embedding ----------------
__global__ void embed_kernel(const int* __restrict__ lang, const float* __restrict__ emb,
                             float* __restrict__ out) {
    int g = blockIdx.x * 256 + threadIdx.x;
    if (g < TBTOT * 32) { int r = g >> 5, c = g & 31; out[g] = emb[lang[r] * 32 + c]; }
}

// ---------------- concat ----------------
__global__ void concat_kernel(const float* __restrict__ img_h, const float* __restrict__ lang_h,
                              float* __restrict__ out) {
    int r = blockIdx.x, c = threadIdx.x;
    out[r * 288 + c] = (c < 256) ? img_h[r * 256 + c] : lang_h[r * 32 + (c - 256)];
}

// ---------------- persistent MFMA LSTM scan (split-bf16, pipelined, group-scoped sync) ----------------
// grid (H/16 j-tiles, 4 b-groups). b-groups are fully independent (h rows disjoint):
// each group of H/16 blocks has its own barrier region. Per step: cooperative xw stage
// via gbuf LDS; h-stage chunks register-prefetched + LDS double-buffered (1 sync/chunk).
template <int H, bool PER_ENV>
__global__ __launch_bounds__(256) void lstm_mfma_kernel(
        const float* __restrict__ xw,      // [T*B][4H]
        const short* __restrict__ wf_hi,
        const short* __restrict__ wf_lo,
        const float* __restrict__ done,
        const float* __restrict__ h0, const float* __restrict__ c0,
        short* __restrict__ hbuf_hi,       // [2][B][H]
        short* __restrict__ hbuf_lo,
        float* __restrict__ hs,            // [T*B][H]
        unsigned* __restrict__ bar_base, unsigned sub_target) {
    constexpr int NCH = H / 256;           // 256-wide k-chunks per step
    __shared__ bf16x8 lsA[2][2][1024];     // [buf][hi/lo][32 rows x 32 segs]
    __shared__ float  gbuf[4][32][16];     // gate exchange; reused for xw staging
    const int t    = threadIdx.x;
    const int lane = t & 63;
    const int q    = t >> 6;
    const int jt   = blockIdx.x;
    const int j0   = jt * 16;
    const int b0   = blockIdx.y * 32;
    const int jl   = t & 15, bl = (t >> 4) & 15;
    const int jg   = j0 + jl;
    const int njt  = H >> 4;
    unsigned* gbar = bar_base + blockIdx.y * 160;
    const unsigned sub = blockIdx.x & 7u;

    float c_reg[2];
    c_reg[0] = c0[(b0 + bl) * H + jg];
    c_reg[1] = c0[(b0 + bl + 16) * H + jg];
    #pragma unroll
    for (int e = 0; e < 2; ++e) {
        int b = b0 + bl + e * 16;
        float v = h0[(size_t)b * H + jg];
        short a = f32_to_bf16_rne(v);
        short l = f32_to_bf16_rne(v - bf16s_to_f32(a));
        hbuf_hi[(size_t)b * H + jg] = a;
        hbuf_lo[(size_t)b * H + jg] = l;
    }
    unsigned bar = 1;
    gridbar2(gbar, bar, sub, sub_target); ++bar;

    const bf16x8 zero8 = {0, 0, 0, 0, 0, 0, 0, 0};
    int cur = 0;
    for (int st = 0; st < T_STEPS; ++st) {
        const short* hsh = hbuf_hi + (size_t)cur * (BATCH * H);
        const short* hsl = hbuf_lo + (size_t)cur * (BATCH * H);
        const bf16x8* bfh = (const bf16x8*)wf_hi + (size_t)(q * njt + jt) * (H >> 5) * 64;
        const bf16x8* bfl = (const bf16x8*)wf_lo + (size_t)(q * njt + jt) * (H >> 5) * 64;
        const float m_step = PER_ENV ? 0.0f : (1.0f - done[st]);

        bf16x8 rA[2][4], rB[2][4];

        auto loadC = [&](bf16x8 (&r)[2][4], int c) {
            const int k0 = c * 256;
            #pragma unroll
            for (int i = 0; i < 4; ++i) {
                int idx = i * 256 + t;
                int row = idx >> 5, seg = idx & 31;
                size_t base = (size_t)(b0 + row) * H + k0 + seg * 8;
                r[0][i] = *(const bf16x8*)&hsh[base];
                r[1][i] = *(const bf16x8*)&hsl[base];
            }
        };
        auto writeC = [&](bf16x8 (&r)[2][4], int bb) {
            #pragma unroll
            for (int i = 0; i < 4; ++i) {
                int idx = i * 256 + t;
                int row = idx >> 5, seg = idx & 31;
                float m = PER_ENV ? (1.0f - done[st * BATCH + b0 + row]) : m_step;
                int slot = seg * 32 + ((row ^ seg) & 31);
                bf16x8 vh = r[0][i], vl = r[1][i];
                if (m == 0.0f) { vh = zero8; vl = zero8; }
                lsA[bb][0][slot] = vh;
                lsA[bb][1][slot] = vl;
            }
        };
        f32x4 acc0 = {0.f, 0.f, 0.f, 0.f};
        f32x4 acc1 = {0.f, 0.f, 0.f, 0.f};
        auto mfmaC = [&](int c) {
            const int bb = c & 1;
            #pragma unroll
            for (int ksl = 0; ksl < 8; ++ksl) {
                int ks = c * 8 + ksl;
                bf16x8 b_hi = bfh[(size_t)ks * 64 + lane];
                bf16x8 b_lo = bfl[(size_t)ks * 64 + lane];
                int kgrp = ksl * 4 + (lane >> 4);
                int r0 = lane & 15, r1 = r0 + 16;
                bf16x8 a0h = lsA[bb][0][kgrp * 32 + ((r0 ^ kgrp) & 31)];
                bf16x8 a0l = lsA[bb][1][kgrp * 32 + ((r0 ^ kgrp) & 31)];
                bf16x8 a1h = lsA[bb][0][kgrp * 32 + ((r1 ^ kgrp) & 31)];
                bf16x8 a1l = lsA[bb][1][kgrp * 32 + ((r1 ^ kgrp) & 31)];
                acc0 = __builtin_amdgcn_mfma_f32_16x16x32_bf16(a0h, b_hi, acc0, 0, 0, 0);
                acc1 = __builtin_amdgcn_mfma_f32_16x16x32_bf16(a1h, b_hi, acc1, 0, 0, 0);
                acc0 = __builtin_amdgcn_mfma_f32_16x16x32_bf16(a0h, b_lo, acc0, 0, 0, 0);
                acc1 = __builtin_amdgcn_mfma_f32_16x16x32_bf16(a1h, b_lo, acc1, 0, 0, 0);
                acc0 = __builtin_amdgcn_mfma_f32_16x16x32_bf16(a0l, b_hi, acc0, 0, 0, 0);
                acc1 = __builtin_amdgcn_mfma_f32_16x16x32_bf16(a1l, b_hi, acc1, 0, 0, 0);
            }
        };

        // prologue: chunk0 loads + coalesced xw stage into gbuf + chunk0 LDS write
        loadC(rA, 0);
        {
            float* gf = &gbuf[0][0][0];
            #pragma unroll
            for (int k = 0; k < 2; ++k) {
                int f = k * 256 + t;                 // [row(32)][gate(4)][j4(4)] float4s
                int row = f >> 4, g4 = (f >> 2) & 3, j4 = f & 3;
                float4 v = *(const float4*)&xw[(size_t)(st * BATCH + b0 + row) * (4 * H)
                                               + g4 * H + j0 + j4 * 4];
                *(float4*)&gf[f * 4] = v;
            }
        }
        writeC(rA, 0);
        __syncthreads();

        // xg + masks from staged LDS
        float xg[2][4], m_e[2];
        {
            const float* gf = &gbuf[0][0][0];
            #pragma unroll
            for (int e = 0; e < 2; ++e) {
                int row = bl + e * 16;
                #pragma unroll
                for (int g4 = 0; g4 < 4; ++g4) xg[e][g4] = gf[row * 64 + g4 * 16 + jl];
                m_e[e] = PER_ENV ? (1.0f - done[st * BATCH + b0 + row]) : m_step;
            }
        }

        #pragma unroll
        for (int c = 0; c < NCH; ++c) {
            if (c + 1 < NCH) {
                if ((c + 1) & 1) loadC(rB, c + 1); else loadC(rA, c + 1);
            }
            mfmaC(c);
            if (c + 1 < NCH) {
                if ((c + 1) & 1) writeC(rB, 1); else writeC(rA, 0);
                __syncthreads();
            }
        }
        __syncthreads();

        #pragma unroll
        for (int r = 0; r < 4; ++r) {
            gbuf[q][(lane >> 4) * 4 + r][lane & 15]      = acc0[r];
            gbuf[q][16 + (lane >> 4) * 4 + r][lane & 15] = acc1[r];
        }
        __syncthreads();

        #pragma unroll
        for (int e = 0; e < 2; ++e) {
            int b_loc = bl + e * 16;
            int bgl = b0 + b_loc;
            float m = m_e[e];
            float gi = gbuf[0][b_loc][jl] + xg[e][0];
            float gf_ = gbuf[1][b_loc][jl] + xg[e][1];
            float gg = gbuf[2][b_loc][jl] + xg[e][2];
            float go = gbuf[3][b_loc][jl] + xg[e][3];
            float cc = fast_sigm(gf_) * (c_reg[e] * m) + fast_sigm(gi) * fast_tanh(gg);
            float hh = fast_sigm(go) * fast_tanh(cc);
            c_reg[e] = cc;
            hs[(size_t)(st * BATCH + bgl) * H + jg] = hh;
            short hhi = f32_to_bf16_rne(hh);
            short hlo = f32_to_bf16_rne(hh - bf16s_to_f32(hhi));
            size_t ho = (size_t)(cur ^ 1) * (BATCH * H) + (size_t)bgl * H + jg;
            hbuf_hi[ho] = hhi;
            hbuf_lo[ho] = hlo;
        }
        gridbar2(gbar, bar, sub, sub_target); ++bar;
        cur ^= 1;
    }
}

extern "C" void kernel_launch(void* const* d_in, const int* in_sizes, int n_in,
                              void* d_out, int out_size, void* d_ws, size_t ws_size,
                              hipStream_t stream) {
    const float* x_img    = (const float*)d_in[0];
    const int*   x_lang   = (const int*)d_in[1];
    const float* done     = (const float*)d_in[2];
    const float* enc_h0   = (const float*)d_in[3];
    const float* enc_c0   = (const float*)d_in[4];
    const float* mem_h0   = (const float*)d_in[5];
    const float* mem_c0   = (const float*)d_in[6];
    const float* emb      = (const float*)d_in[7];
    const float* conv1_w  = (const float*)d_in[8];
    const float* conv1_b  = (const float*)d_in[9];
    const float* conv2_w  = (const float*)d_in[10];
    const float* conv2_b  = (const float*)d_in[11];
    const float* conv3_w  = (const float*)d_in[12];
    const float* conv3_b  = (const float*)d_in[13];
    const float* fc_w     = (const float*)d_in[14];
    const float* fc_b     = (const float*)d_in[15];
    const float* enc_Wih  = (const float*)d_in[16];
    const float* enc_Whh  = (const float*)d_in[17];
    const float* enc_bih  = (const float*)d_in[18];
    const float* enc_bhh  = (const float*)d_in[19];
    const float* lemb_w   = (const float*)d_in[20];
    const float* lemb_b   = (const float*)d_in[21];
    const float* mem_Wih  = (const float*)d_in[22];
    const float* mem_Whh  = (const float*)d_in[23];
    const float* mem_bih  = (const float*)d_in[24];
    const float* mem_bhh  = (const float*)d_in[25];
    const float* actor_w  = (const float*)d_in[26];
    const float* actor_b  = (const float*)d_in[27];
    const float* critic_w = (const float*)d_in[28];
    const float* critic_b = (const float*)d_in[29];

    float* ws = (float*)d_ws;
    float* conv3_flat = ws + OFF_CONV3;
    short* mem_wf_hi  = (short*)(ws + OFF_MWFHI);
    short* mem_wf_lo  = (short*)(ws + OFF_MWFLO);
    short* enc_wf_hi  = (short*)(ws + OFF_EWFHI);
    short* enc_wf_lo  = (short*)(ws + OFF_EWFLO);
    short* hbm_hi     = (short*)(ws + OFF_HBMHI);
    short* hbm_lo     = (short*)(ws + OFF_HBMLO);
    short* hbe_hi     = (short*)(ws + OFF_HBEHI);
    short* hbe_lo     = (short*)(ws + OFF_HBELO);
    float* img_hidden = ws + OFF_IMGH;
    float* lang_in    = ws + OFF_LANGIN;
    float* enc_xW     = ws + OFF_ENCXW;
    float* enc_hs     = ws + OFF_ENCHS;
    float* lang_h     = ws + OFF_LANGH;
    float* hidden     = ws + OFF_HIDDEN;
    float* mem_xW     = ws + OFF_MEMXW;
    float* mem_hs     = ws + OFF_MEMHS;
    float* enc_bc     = ws + OFF_ENCBC;
    float* mem_bc     = ws + OFF_MEMBC;
    float* head_w     = ws + OFF_HEADW;
    float* head_b     = ws + OFF_HEADB;
    unsigned* bars    = (unsigned*)(ws + OFF_BARS);

    prep_kernel<<<64, 256, 0, stream>>>(enc_bih, enc_bhh, mem_bih, mem_bhh,
                                        actor_w, actor_b, critic_w, critic_b,
                                        enc_bc, mem_bc, head_w, head_b, bars);
    conv_kernel<<<TBTOT, 256, 0, stream>>>(x_img, conv1_w, conv1_b, conv2_w, conv2_b,
                                           conv3_w, conv3_b, conv3_flat);
    gemm64<true><<<dim3(128, 4), 64, 0, stream>>>(conv3_flat, fc_w, fc_b, img_hidden, TBTOT, 256, 1568);
    // conv3 region dead from here; build LSTM split-weight fragments in it
    split_frag_kernel<<<65536, 256, 0, stream>>>(mem_Whh, mem_wf_hi, mem_wf_lo, 1024);
    split_frag_kernel<<<4096, 256, 0, stream>>>(enc_Whh, enc_wf_hi, enc_wf_lo, 256);
    embed_kernel<<<1024, 256, 0, stream>>>(x_lang, emb, lang_in);
    gemm64<false><<<dim3(128, 16), 64, 0, stream>>>(lang_in, enc_Wih, enc_bc, enc_xW, TBTOT, 1024, 32);
    lstm_mfma_kernel<256, false><<<dim3(16, 4), 256, 0, stream>>>(
        enc_xW, enc_wf_hi, enc_wf_lo, done, enc_h0, enc_c0, hbe_hi, hbe_lo, enc_hs,
        bars + 0, 2u);
    gemm64<true><<<dim3(128, 1), 64, 0, stream>>>(enc_hs, lemb_w, lemb_b, lang_h, TBTOT, 32, 256);
    concat_kernel<<<TBTOT, 288, 0, stream>>>(img_hidden, lang_h, hidden);
    gemm64<false><<<dim3(128, 64), 64, 0, stream>>>(hidden, mem_Wih, mem_bc, mem_xW, TBTOT, 4096, 288);
    lstm_mfma_kernel<1024, true><<<dim3(64, 4), 256, 0, stream>>>(
        mem_xW, mem_wf_hi, mem_wf_lo, done, mem_h0, mem_c0, hbm_hi, hbm_lo, mem_hs,
        bars + 640, 8u);
    gemm64<false><<<dim3(128, 1), 64, 0, stream>>>(mem_hs, head_w, head_b, (float*)d_out, TBTOT, 16, 1024);
}

// Round 6
// 3748.433 us; speedup vs baseline: 1.1083x; 1.1083x over previous
//
#include <hip/hip_runtime.h>
#include <math.h>

#define T_STEPS 64
#define BATCH   128
#define TBTOT   8192

typedef __attribute__((ext_vector_type(8))) short bf16x8;
typedef __attribute__((ext_vector_type(4))) float f32x4;

// ---------------- workspace layout (float offsets) ----------------
static const size_t OFF_CONV3  = 0;              // [8192][1568] f32 (phase 1)
static const size_t OFF_MWFHI  = 0;              // [4096*1024] bf16  (phase 2)
static const size_t OFF_MWFLO  = 2097152;        // [4096*1024] bf16
static const size_t OFF_EWFHI  = 4194304;        // [1024*256] bf16
static const size_t OFF_EWFLO  = 4325376;        // [1024*256] bf16
static const size_t OFF_HBMHI  = 4456448;        // [2][128][1024] bf16
static const size_t OFF_HBMLO  = 4587520;        // [2][128][1024] bf16
static const size_t OFF_HBEHI  = 4718592;        // [2][128][256] bf16
static const size_t OFF_HBELO  = 4734976;        // [2][128][256] bf16
static const size_t OFF_IMGH   = 12845056;       // [8192][256]
static const size_t OFF_LANGIN = 14942208;       // [8192][32]
static const size_t OFF_ENCXW  = 15204352;       // [8192][1024]
static const size_t OFF_ENCHS  = 23592960;       // [8192][256]
static const size_t OFF_LANGH  = 25690112;       // [8192][32]
static const size_t OFF_HIDDEN = 25952256;       // [8192][288]
static const size_t OFF_MEMXW  = 28311552;       // [8192][4096]
static const size_t OFF_MEMHS  = 61865984;       // [8192][1024]
static const size_t OFF_ENCBC  = 70582272;       // [1024]
static const size_t OFF_MEMBC  = 70583296;       // [4096]
static const size_t OFF_HEADW  = 70587392;       // [16][1024]
static const size_t OFF_HEADB  = 70603776;       // [16]
static const size_t OFF_BARS   = 70603792;       // 1280 uints (per-group barrier counters)

__device__ __forceinline__ float fast_sigm(float x) { return 1.0f / (1.0f + __expf(-x)); }
__device__ __forceinline__ float fast_tanh(float x) { return 2.0f / (1.0f + __expf(-2.0f * x)) - 1.0f; }

__device__ __forceinline__ short f32_to_bf16_rne(float x) {
    unsigned u = __float_as_uint(x);
    unsigned r = (u + 0x7fffu + ((u >> 16) & 1u)) >> 16;
    return (short)r;
}
__device__ __forceinline__ float bf16s_to_f32(short s) {
    return __uint_as_float(((unsigned)(unsigned short)s) << 16);
}

// -------- per-group hierarchical barrier, relaxed spin + single acquire fence --------
// Group region (160 uints): 8 sub-counters at [s*16] (own 64B lines), phase at [128].
// Arrivals RELEASE; spin is RELAXED (no per-poll cache invalidate); ONE acquire
// fence on exit provides the invalidate before reading remote data.
__device__ __forceinline__ void gridbar2(unsigned* g, unsigned round,
                                         unsigned sub, unsigned sub_target) {
    __syncthreads();
    if (threadIdx.x == 0) {
        __threadfence();  // drain prior global writes toward coherence point
        unsigned old = __hip_atomic_fetch_add(&g[sub * 16], 1u,
                                              __ATOMIC_RELEASE, __HIP_MEMORY_SCOPE_AGENT);
        if (old + 1u == sub_target * round) {
            __hip_atomic_fetch_add(&g[128], 1u,
                                   __ATOMIC_RELEASE, __HIP_MEMORY_SCOPE_AGENT);
        }
        while (__hip_atomic_load(&g[128], __ATOMIC_RELAXED,
                                 __HIP_MEMORY_SCOPE_AGENT) < 8u * round) {
            __builtin_amdgcn_s_sleep(2);
        }
        __builtin_amdgcn_fence(__ATOMIC_ACQUIRE, "agent");
    }
    __syncthreads();
}

// ---------------- prep ----------------
__global__ void prep_kernel(const float* __restrict__ enc_bih, const float* __restrict__ enc_bhh,
                            const float* __restrict__ mem_bih, const float* __restrict__ mem_bhh,
                            const float* __restrict__ actor_w, const float* __restrict__ actor_b,
                            const float* __restrict__ critic_w, const float* __restrict__ critic_b,
                            float* __restrict__ enc_bc, float* __restrict__ mem_bc,
                            float* __restrict__ head_w, float* __restrict__ head_b,
                            unsigned* __restrict__ bars) {
    int g = blockIdx.x * 256 + threadIdx.x;
    if (g < 1024)  enc_bc[g] = enc_bih[g] + enc_bhh[g];
    if (g < 4096)  mem_bc[g] = mem_bih[g] + mem_bhh[g];
    if (g < 16384) { int j = g >> 10, k = g & 1023; head_w[g] = (j < 15) ? actor_w[j * 1024 + k] : critic_w[k]; }
    if (g < 16)    head_b[g] = (g < 15) ? actor_b[g] : critic_b[0];
    if (g < 1280)  bars[g] = 0u;
}

// ---------------- split Whh into MFMA-fragment-ordered bf16 hi/lo ----------------
__global__ void split_frag_kernel(const float* __restrict__ W, short* __restrict__ hi,
                                  short* __restrict__ lo, int H) {
    size_t f = (size_t)blockIdx.x * 256 + threadIdx.x;
    size_t total = (size_t)4 * H * H;
    if (f >= total) return;
    int e    = (int)(f & 7);
    int lane = (int)((f >> 3) & 63);
    size_t rest = f >> 9;
    int nks = H >> 5;
    int ks  = (int)(rest % nks);
    int qjt = (int)(rest / nks);
    int njt = H >> 4;
    int qq = qjt / njt, jt = qjt - qq * njt;
    int n = qq * H + jt * 16 + (lane & 15);
    int k = ks * 32 + (lane >> 4) * 8 + e;
    float w = W[(size_t)n * H + k];
    short a = f32_to_bf16_rne(w);
    short b = f32_to_bf16_rne(w - bf16s_to_f32(a));
    hi[f] = a; lo[f] = b;
}

// ---------------- fused conv stack, one block per image ----------------
__global__ __launch_bounds__(256) void conv_kernel(const float* __restrict__ x,
        const float* __restrict__ w1, const float* __restrict__ b1,
        const float* __restrict__ w2, const float* __restrict__ b2,
        const float* __restrict__ w3, const float* __restrict__ b3,
        float* __restrict__ out) {
    __shared__ float arena[16384];
    const int t = threadIdx.x;
    const size_t img = blockIdx.x;

    float* s_out1 = arena;
    float* s_w1   = arena + 1936;
    float* s_b1   = arena + 3232;
    float* s_img  = arena + 3248;
    const float* xi = x + img * 9801;
    for (int i = t; i < 9801; i += 256) s_img[i] = xi[i] * (1.0f / 255.0f);
    for (int i = t; i < 1296; i += 256) s_w1[i] = w1[i];
    if (t < 16) s_b1[t] = b1[t];
    __syncthreads();

    if (t < 176) {
        int c = t / 11, i = t - c * 11;
        float accr[11];
        #pragma unroll
        for (int j = 0; j < 11; ++j) accr[j] = s_b1[c];
        for (int ky = 0; ky < 9; ++ky) {
            const float* irow = s_img + (i * 9 + ky) * 99;
            const float* wrow = s_w1 + c * 81 + ky * 9;
            for (int kx = 0; kx < 9; ++kx) {
                float wv = wrow[kx];
                #pragma unroll
                for (int j = 0; j < 11; ++j) accr[j] += wv * irow[j * 9 + kx];
            }
        }
        #pragma unroll
        for (int j = 0; j < 11; ++j) s_out1[c * 121 + i * 11 + j] = fmaxf(accr[j], 0.0f);
    }
    __syncthreads();

    float* s_w2   = arena + 1936;
    float* s_b2   = arena + 6544;
    float* s_out2 = arena + 13792;
    for (int i = t; i < 4608; i += 256) s_w2[i] = w2[i];
    if (t < 32) s_b2[t] = b2[t];
    __syncthreads();

    for (int rr = 0; rr < 2; ++rr) {
        int task = rr * 256 + t;
        if (task < 288) {
            int c = task / 9, i = task - c * 9;
            float accr[9];
            #pragma unroll
            for (int j = 0; j < 9; ++j) accr[j] = s_b2[c];
            for (int ic = 0; ic < 16; ++ic) {
                const float* ibase = s_out1 + ic * 121 + i * 11;
                const float* wbase = s_w2 + (c * 16 + ic) * 9;
                #pragma unroll
                for (int ky = 0; ky < 3; ++ky) {
                    const float* irow = ibase + ky * 11;
                    #pragma unroll
                    for (int kx = 0; kx < 3; ++kx) {
                        float wv = wbase[ky * 3 + kx];
                        #pragma unroll
                        for (int j = 0; j < 9; ++j) accr[j] += wv * irow[j + kx];
                    }
                }
            }
            #pragma unroll
            for (int j = 0; j < 9; ++j) s_out2[c * 81 + i * 9 + j] = fmaxf(accr[j], 0.0f);
        }
    }
    __syncthreads();

    float* s_w3   = arena;
    float* s_b3   = arena + 9216;
    float* s_out3 = arena + 9248;
    for (int i = t; i < 9216; i += 256) s_w3[i] = w3[i];
    if (t < 32) s_b3[t] = b3[t];
    __syncthreads();

    if (t < 224) {
        int c = t / 7, i = t - c * 7;
        float accr[7];
        #pragma unroll
        for (int j = 0; j < 7; ++j) accr[j] = s_b3[c];
        for (int ic = 0; ic < 32; ++ic) {
            const float* ibase = s_out2 + ic * 81 + i * 9;
            const float* wbase = s_w3 + (c * 32 + ic) * 9;
            #pragma unroll
            for (int ky = 0; ky < 3; ++ky) {
                const float* irow = ibase + ky * 9;
                #pragma unroll
                for (int kx = 0; kx < 3; ++kx) {
                    float wv = wbase[ky * 3 + kx];
                    #pragma unroll
                    for (int j = 0; j < 7; ++j) accr[j] += wv * irow[j + kx];
                }
            }
        }
        #pragma unroll
        for (int j = 0; j < 7; ++j) s_out3[c * 49 + i * 7 + j] = fmaxf(accr[j], 0.0f);
    }
    __syncthreads();
    float* og = out + img * 1568;
    for (int i = t; i < 1568; i += 256) og[i] = s_out3[i];
}

// ---------------- generic tiled GEMM ----------------
template <bool RELU>
__global__ __launch_bounds__(64) void gemm64(const float* __restrict__ A, const float* __restrict__ W,
                                             const float* __restrict__ bias, float* __restrict__ C,
                                             int M, int N, int K) {
    __shared__ float At[32][68];
    __shared__ float Wt[32][68];
    const int m0 = blockIdx.x * 64, n0 = blockIdx.y * 64;
    const int t = threadIdx.x;
    const int tx = t & 7, ty = t >> 3;
    float acc[8][8] = {};
    for (int kc = 0; kc < K; kc += 32) {
        #pragma unroll
        for (int i = 0; i < 8; ++i) {
            int e = t + i * 64;
            int row = e >> 3, c4 = (e & 7) * 4;
            float4 v = *(const float4*)&A[(size_t)(m0 + row) * K + kc + c4];
            At[c4 + 0][row] = v.x; At[c4 + 1][row] = v.y; At[c4 + 2][row] = v.z; At[c4 + 3][row] = v.w;
            int n = n0 + row;
            float4 wv = make_float4(0.f, 0.f, 0.f, 0.f);
            if (n < N) wv = *(const float4*)&W[(size_t)n * K + kc + c4];
            Wt[c4 + 0][row] = wv.x; Wt[c4 + 1][row] = wv.y; Wt[c4 + 2][row] = wv.z; Wt[c4 + 3][row] = wv.w;
        }
        __syncthreads();
        #pragma unroll
        for (int kk = 0; kk < 32; ++kk) {
            float4 a0 = *(const float4*)&At[kk][ty * 8];
            float4 a1 = *(const float4*)&At[kk][ty * 8 + 4];
            float4 b0 = *(const float4*)&Wt[kk][tx * 8];
            float4 b1 = *(const float4*)&Wt[kk][tx * 8 + 4];
            float a[8] = {a0.x, a0.y, a0.z, a0.w, a1.x, a1.y, a1.z, a1.w};
            float b[8] = {b0.x, b0.y, b0.z, b0.w, b1.x, b1.y, b1.z, b1.w};
            #pragma unroll
            for (int i = 0; i < 8; ++i)
                #pragma unroll
                for (int j = 0; j < 8; ++j) acc[i][j] += a[i] * b[j];
        }
        __syncthreads();
    }
    #pragma unroll
    for (int i = 0; i < 8; ++i) {
        int m = m0 + ty * 8 + i;
        #pragma unroll
        for (int j = 0; j < 8; ++j) {
            int n = n0 + tx * 8 + j;
            if (n < N) {
                float v = acc[i][j] + bias[n];
                if (RELU) v = fmaxf(v, 0.0f);
                C[(size_t)m * N + n] = v;
            }
        }
    }
}

// ---------------- embedding ----------------
__global__ void embed_kernel(const int* __restrict__ lang, const float* __restrict__ emb,
                             float* __restrict__ out) {
    int g = blockIdx.x * 256 + threadIdx.x;
    if (g < TBTOT * 32) { int r = g >> 5, c = g & 31; out[g] = emb[lang[r] * 32 + c]; }
}

// ---------------- concat ----------------
__global__ void concat_kernel(const float* __restrict__ img_h, const float* __restrict__ lang_h,
                              float* __restrict__ out) {
    int r = blockIdx.x, c = threadIdx.x;
    out[r * 288 + c] = (c < 256) ? img_h[r * 256 + c] : lang_h[r * 32 + (c - 256)];
}

// ---------------- persistent MFMA LSTM scan (split-bf16, 3-pass, R3 body + new barrier) ----------------
// grid (H/16 j-tiles, 4 b-groups); b-groups fully independent with own barrier regions.
template <int H, bool PER_ENV>
__global__ __launch_bounds__(256) void lstm_mfma_kernel(
        const float* __restrict__ xw,      // [T*B][4H]
        const short* __restrict__ wf_hi,
        const short* __restrict__ wf_lo,
        const float* __restrict__ done,
        const float* __restrict__ h0, const float* __restrict__ c0,
        short* __restrict__ hbuf_hi,       // [2][B][H]
        short* __restrict__ hbuf_lo,
        float* __restrict__ hs,            // [T*B][H]
        unsigned* __restrict__ bar_base, unsigned sub_target) {
    __shared__ bf16x8 lsA[2][1024];
    __shared__ float  gbuf[4][32][16];
    const int t    = threadIdx.x;
    const int lane = t & 63;
    const int q    = t >> 6;
    const int jt   = blockIdx.x;
    const int j0   = jt * 16;
    const int b0   = blockIdx.y * 32;
    const int jl   = t & 15, bl = (t >> 4) & 15;
    const int jg   = j0 + jl;
    const int njt  = H >> 4, nks = H >> 5;
    unsigned* gbar = bar_base + blockIdx.y * 160;
    const unsigned sub = blockIdx.x & 7u;

    float c_reg[2];
    c_reg[0] = c0[(b0 + bl) * H + jg];
    c_reg[1] = c0[(b0 + bl + 16) * H + jg];
    #pragma unroll
    for (int e = 0; e < 2; ++e) {
        int b = b0 + bl + e * 16;
        float v = h0[(size_t)b * H + jg];
        short a = f32_to_bf16_rne(v);
        short l = f32_to_bf16_rne(v - bf16s_to_f32(a));
        hbuf_hi[(size_t)b * H + jg] = a;
        hbuf_lo[(size_t)b * H + jg] = l;
    }
    unsigned bar = 1;
    gridbar2(gbar, bar, sub, sub_target); ++bar;

    const bf16x8 zero8 = {0, 0, 0, 0, 0, 0, 0, 0};
    int cur = 0;
    for (int st = 0; st < T_STEPS; ++st) {
        // prefetch xw gate values (independent of h)
        float m_step = PER_ENV ? 0.0f : (1.0f - done[st]);
        float xg[2][4];
        float m_e[2];
        #pragma unroll
        for (int e = 0; e < 2; ++e) {
            int bgl = b0 + bl + e * 16;
            const float* xr = xw + (size_t)(st * BATCH + bgl) * (4 * H);
            #pragma unroll
            for (int g4 = 0; g4 < 4; ++g4) xg[e][g4] = xr[g4 * H + jg];
            m_e[e] = PER_ENV ? (1.0f - done[st * BATCH + bgl]) : m_step;
        }

        f32x4 acc0 = {0.f, 0.f, 0.f, 0.f};
        f32x4 acc1 = {0.f, 0.f, 0.f, 0.f};
        const short* hsh = hbuf_hi + (size_t)cur * (BATCH * H);
        const short* hsl = hbuf_lo + (size_t)cur * (BATCH * H);
        const bf16x8* bfh = (const bf16x8*)wf_hi + (size_t)(q * njt + jt) * nks * 64;
        const bf16x8* bfl = (const bf16x8*)wf_lo + (size_t)(q * njt + jt) * nks * 64;

        for (int cch = 0; cch < H / 256; ++cch) {
            const int k0 = cch * 256;
            #pragma unroll
            for (int i = 0; i < 4; ++i) {
                int idx = i * 256 + t;
                int row = idx >> 5, seg = idx & 31;
                float m = PER_ENV ? (1.0f - done[st * BATCH + b0 + row]) : m_step;
                int slot = seg * 32 + ((row ^ seg) & 31);
                bf16x8 vh = *(const bf16x8*)&hsh[(size_t)(b0 + row) * H + k0 + seg * 8];
                bf16x8 vl = *(const bf16x8*)&hsl[(size_t)(b0 + row) * H + k0 + seg * 8];
                if (m == 0.0f) { vh = zero8; vl = zero8; }
                lsA[0][slot] = vh;
                lsA[1][slot] = vl;
            }
            __syncthreads();
            #pragma unroll
            for (int ksl = 0; ksl < 8; ++ksl) {
                int ks = (k0 >> 5) + ksl;
                bf16x8 b_hi = bfh[(size_t)ks * 64 + lane];
                bf16x8 b_lo = bfl[(size_t)ks * 64 + lane];
                int kgrp = ksl * 4 + (lane >> 4);
                int r0 = lane & 15, r1 = r0 + 16;
                bf16x8 a0h = lsA[0][kgrp * 32 + ((r0 ^ kgrp) & 31)];
                bf16x8 a0l = lsA[1][kgrp * 32 + ((r0 ^ kgrp) & 31)];
                bf16x8 a1h = lsA[0][kgrp * 32 + ((r1 ^ kgrp) & 31)];
                bf16x8 a1l = lsA[1][kgrp * 32 + ((r1 ^ kgrp) & 31)];
                acc0 = __builtin_amdgcn_mfma_f32_16x16x32_bf16(a0h, b_hi, acc0, 0, 0, 0);
                acc1 = __builtin_amdgcn_mfma_f32_16x16x32_bf16(a1h, b_hi, acc1, 0, 0, 0);
                acc0 = __builtin_amdgcn_mfma_f32_16x16x32_bf16(a0h, b_lo, acc0, 0, 0, 0);
                acc1 = __builtin_amdgcn_mfma_f32_16x16x32_bf16(a1h, b_lo, acc1, 0, 0, 0);
                acc0 = __builtin_amdgcn_mfma_f32_16x16x32_bf16(a0l, b_hi, acc0, 0, 0, 0);
                acc1 = __builtin_amdgcn_mfma_f32_16x16x32_bf16(a1l, b_hi, acc1, 0, 0, 0);
            }
            __syncthreads();
        }

        #pragma unroll
        for (int r = 0; r < 4; ++r) {
            gbuf[q][(lane >> 4) * 4 + r][lane & 15]      = acc0[r];
            gbuf[q][16 + (lane >> 4) * 4 + r][lane & 15] = acc1[r];
        }
        __syncthreads();

        #pragma unroll
        for (int e = 0; e < 2; ++e) {
            int b_loc = bl + e * 16;
            int bgl = b0 + b_loc;
            float m = m_e[e];
            float gi = gbuf[0][b_loc][jl] + xg[e][0];
            float gf = gbuf[1][b_loc][jl] + xg[e][1];
            float gg = gbuf[2][b_loc][jl] + xg[e][2];
            float go = gbuf[3][b_loc][jl] + xg[e][3];
            float cc = fast_sigm(gf) * (c_reg[e] * m) + fast_sigm(gi) * fast_tanh(gg);
            float hh = fast_sigm(go) * fast_tanh(cc);
            c_reg[e] = cc;
            hs[(size_t)(st * BATCH + bgl) * H + jg] = hh;
            short hhi = f32_to_bf16_rne(hh);
            short hlo = f32_to_bf16_rne(hh - bf16s_to_f32(hhi));
            size_t ho = (size_t)(cur ^ 1) * (BATCH * H) + (size_t)bgl * H + jg;
            hbuf_hi[ho] = hhi;
            hbuf_lo[ho] = hlo;
        }
        gridbar2(gbar, bar, sub, sub_target); ++bar;
        cur ^= 1;
    }
}

extern "C" void kernel_launch(void* const* d_in, const int* in_sizes, int n_in,
                              void* d_out, int out_size, void* d_ws, size_t ws_size,
                              hipStream_t stream) {
    const float* x_img    = (const float*)d_in[0];
    const int*   x_lang   = (const int*)d_in[1];
    const float* done     = (const float*)d_in[2];
    const float* enc_h0   = (const float*)d_in[3];
    const float* enc_c0   = (const float*)d_in[4];
    const float* mem_h0   = (const float*)d_in[5];
    const float* mem_c0   = (const float*)d_in[6];
    const float* emb      = (const float*)d_in[7];
    const float* conv1_w  = (const float*)d_in[8];
    const float* conv1_b  = (const float*)d_in[9];
    const float* conv2_w  = (const float*)d_in[10];
    const float* conv2_b  = (const float*)d_in[11];
    const float* conv3_w  = (const float*)d_in[12];
    const float* conv3_b  = (const float*)d_in[13];
    const float* fc_w     = (const float*)d_in[14];
    const float* fc_b     = (const float*)d_in[15];
    const float* enc_Wih  = (const float*)d_in[16];
    const float* enc_Whh  = (const float*)d_in[17];
    const float* enc_bih  = (const float*)d_in[18];
    const float* enc_bhh  = (const float*)d_in[19];
    const float* lemb_w   = (const float*)d_in[20];
    const float* lemb_b   = (const float*)d_in[21];
    const float* mem_Wih  = (const float*)d_in[22];
    const float* mem_Whh  = (const float*)d_in[23];
    const float* mem_bih  = (const float*)d_in[24];
    const float* mem_bhh  = (const float*)d_in[25];
    const float* actor_w  = (const float*)d_in[26];
    const float* actor_b  = (const float*)d_in[27];
    const float* critic_w = (const float*)d_in[28];
    const float* critic_b = (const float*)d_in[29];

    float* ws = (float*)d_ws;
    float* conv3_flat = ws + OFF_CONV3;
    short* mem_wf_hi  = (short*)(ws + OFF_MWFHI);
    short* mem_wf_lo  = (short*)(ws + OFF_MWFLO);
    short* enc_wf_hi  = (short*)(ws + OFF_EWFHI);
    short* enc_wf_lo  = (short*)(ws + OFF_EWFLO);
    short* hbm_hi     = (short*)(ws + OFF_HBMHI);
    short* hbm_lo     = (short*)(ws + OFF_HBMLO);
    short* hbe_hi     = (short*)(ws + OFF_HBEHI);
    short* hbe_lo     = (short*)(ws + OFF_HBELO);
    float* img_hidden = ws + OFF_IMGH;
    float* lang_in    = ws + OFF_LANGIN;
    float* enc_xW     = ws + OFF_ENCXW;
    float* enc_hs     = ws + OFF_ENCHS;
    float* lang_h     = ws + OFF_LANGH;
    float* hidden     = ws + OFF_HIDDEN;
    float* mem_xW     = ws + OFF_MEMXW;
    float* mem_hs     = ws + OFF_MEMHS;
    float* enc_bc     = ws + OFF_ENCBC;
    float* mem_bc     = ws + OFF_MEMBC;
    float* head_w     = ws + OFF_HEADW;
    float* head_b     = ws + OFF_HEADB;
    unsigned* bars    = (unsigned*)(ws + OFF_BARS);

    prep_kernel<<<64, 256, 0, stream>>>(enc_bih, enc_bhh, mem_bih, mem_bhh,
                                        actor_w, actor_b, critic_w, critic_b,
                                        enc_bc, mem_bc, head_w, head_b, bars);
    conv_kernel<<<TBTOT, 256, 0, stream>>>(x_img, conv1_w, conv1_b, conv2_w, conv2_b,
                                           conv3_w, conv3_b, conv3_flat);
    gemm64<true><<<dim3(128, 4), 64, 0, stream>>>(conv3_flat, fc_w, fc_b, img_hidden, TBTOT, 256, 1568);
    // conv3 region dead from here; build LSTM split-weight fragments in it
    split_frag_kernel<<<65536, 256, 0, stream>>>(mem_Whh, mem_wf_hi, mem_wf_lo, 1024);
    split_frag_kernel<<<4096, 256, 0, stream>>>(enc_Whh, enc_wf_hi, enc_wf_lo, 256);
    embed_kernel<<<1024, 256, 0, stream>>>(x_lang, emb, lang_in);
    gemm64<false><<<dim3(128, 16), 64, 0, stream>>>(lang_in, enc_Wih, enc_bc, enc_xW, TBTOT, 1024, 32);
    lstm_mfma_kernel<256, false><<<dim3(16, 4), 256, 0, stream>>>(
        enc_xW, enc_wf_hi, enc_wf_lo, done, enc_h0, enc_c0, hbe_hi, hbe_lo, enc_hs,
        bars + 0, 2u);
    gemm64<true><<<dim3(128, 1), 64, 0, stream>>>(enc_hs, lemb_w, lemb_b, lang_h, TBTOT, 32, 256);
    concat_kernel<<<TBTOT, 288, 0, stream>>>(img_hidden, lang_h, hidden);
    gemm64<false><<<dim3(128, 64), 64, 0, stream>>>(hidden, mem_Wih, mem_bc, mem_xW, TBTOT, 4096, 288);
    lstm_mfma_kernel<1024, true><<<dim3(64, 4), 256, 0, stream>>>(
        mem_xW, mem_wf_hi, mem_wf_lo, done, mem_h0, mem_c0, hbm_hi, hbm_lo, mem_hs,
        bars + 640, 8u);
    gemm64<false><<<dim3(128, 1), 64, 0, stream>>>(mem_hs, head_w, head_b, (float*)d_out, TBTOT, 16, 1024);
}

// Round 7
// 3557.010 us; speedup vs baseline: 1.1680x; 1.0538x over previous
//
#include <hip/hip_runtime.h>
#include <math.h>

#define T_STEPS 64
#define BATCH   128
#define TBTOT   8192

typedef __attribute__((ext_vector_type(8))) short bf16x8;
typedef __attribute__((ext_vector_type(4))) float f32x4;

// ---------------- workspace layout (float offsets) ----------------
static const size_t OFF_CONV3  = 0;              // [8192][1568] f32 (phase 1)
static const size_t OFF_MWFHI  = 0;              // [4096*1024] bf16  (phase 2)
static const size_t OFF_MWFLO  = 2097152;        // [4096*1024] bf16
static const size_t OFF_EWFHI  = 4194304;        // [1024*256] bf16
static const size_t OFF_EWFLO  = 4325376;        // [1024*256] bf16
static const size_t OFF_HBMHI  = 4456448;        // [2][128][1024] bf16
static const size_t OFF_HBMLO  = 4587520;        // [2][128][1024] bf16
static const size_t OFF_HBEHI  = 4718592;        // [2][128][256] bf16
static const size_t OFF_HBELO  = 4734976;        // [2][128][256] bf16
static const size_t OFF_IMGH   = 12845056;       // [8192][256]
static const size_t OFF_LANGIN = 14942208;       // [8192][32]
static const size_t OFF_ENCXW  = 15204352;       // [8192][1024]
static const size_t OFF_ENCHS  = 23592960;       // [8192][256]
static const size_t OFF_LANGH  = 25690112;       // [8192][32]
static const size_t OFF_HIDDEN = 25952256;       // [8192][288]
static const size_t OFF_MEMXW  = 28311552;       // [8192][4096]
static const size_t OFF_MEMHS  = 61865984;       // [8192][1024]
static const size_t OFF_ENCBC  = 70582272;       // [1024]
static const size_t OFF_MEMBC  = 70583296;       // [4096]
static const size_t OFF_HEADW  = 70587392;       // [16][1024]
static const size_t OFF_HEADB  = 70603776;       // [16]
static const size_t OFF_BARS   = 70603792;       // 1280 uints (per-group barrier counters)

__device__ __forceinline__ float fast_sigm(float x) { return 1.0f / (1.0f + __expf(-x)); }
__device__ __forceinline__ float fast_tanh(float x) { return 2.0f / (1.0f + __expf(-2.0f * x)) - 1.0f; }

__device__ __forceinline__ short f32_to_bf16_rne(float x) {
    unsigned u = __float_as_uint(x);
    unsigned r = (u + 0x7fffu + ((u >> 16) & 1u)) >> 16;
    return (short)r;
}
__device__ __forceinline__ float bf16s_to_f32(short s) {
    return __uint_as_float(((unsigned)(unsigned short)s) << 16);
}

// -------- per-group hierarchical barrier, relaxed spin + single acquire fence --------
__device__ __forceinline__ void gridbar2(unsigned* g, unsigned round,
                                         unsigned sub, unsigned sub_target) {
    __syncthreads();
    if (threadIdx.x == 0) {
        __threadfence();
        unsigned old = __hip_atomic_fetch_add(&g[sub * 16], 1u,
                                              __ATOMIC_RELEASE, __HIP_MEMORY_SCOPE_AGENT);
        if (old + 1u == sub_target * round) {
            __hip_atomic_fetch_add(&g[128], 1u,
                                   __ATOMIC_RELEASE, __HIP_MEMORY_SCOPE_AGENT);
        }
        while (__hip_atomic_load(&g[128], __ATOMIC_RELAXED,
                                 __HIP_MEMORY_SCOPE_AGENT) < 8u * round) {
            __builtin_amdgcn_s_sleep(2);
        }
        __builtin_amdgcn_fence(__ATOMIC_ACQUIRE, "agent");
    }
    __syncthreads();
}

// ---------------- prep ----------------
__global__ void prep_kernel(const float* __restrict__ enc_bih, const float* __restrict__ enc_bhh,
                            const float* __restrict__ mem_bih, const float* __restrict__ mem_bhh,
                            const float* __restrict__ actor_w, const float* __restrict__ actor_b,
                            const float* __restrict__ critic_w, const float* __restrict__ critic_b,
                            float* __restrict__ enc_bc, float* __restrict__ mem_bc,
                            float* __restrict__ head_w, float* __restrict__ head_b,
                            unsigned* __restrict__ bars) {
    int g = blockIdx.x * 256 + threadIdx.x;
    if (g < 1024)  enc_bc[g] = enc_bih[g] + enc_bhh[g];
    if (g < 4096)  mem_bc[g] = mem_bih[g] + mem_bhh[g];
    if (g < 16384) { int j = g >> 10, k = g & 1023; head_w[g] = (j < 15) ? actor_w[j * 1024 + k] : critic_w[k]; }
    if (g < 16)    head_b[g] = (g < 15) ? actor_b[g] : critic_b[0];
    if (g < 1280)  bars[g] = 0u;
}

// ---------------- split Whh into MFMA-fragment-ordered bf16 hi/lo ----------------
__global__ void split_frag_kernel(const float* __restrict__ W, short* __restrict__ hi,
                                  short* __restrict__ lo, int H) {
    size_t f = (size_t)blockIdx.x * 256 + threadIdx.x;
    size_t total = (size_t)4 * H * H;
    if (f >= total) return;
    int e    = (int)(f & 7);
    int lane = (int)((f >> 3) & 63);
    size_t rest = f >> 9;
    int nks = H >> 5;
    int ks  = (int)(rest % nks);
    int qjt = (int)(rest / nks);
    int njt = H >> 4;
    int qq = qjt / njt, jt = qjt - qq * njt;
    int n = qq * H + jt * 16 + (lane & 15);
    int k = ks * 32 + (lane >> 4) * 8 + e;
    float w = W[(size_t)n * H + k];
    short a = f32_to_bf16_rne(w);
    short b = f32_to_bf16_rne(w - bf16s_to_f32(a));
    hi[f] = a; lo[f] = b;
}

// ---------------- fused conv stack, one block per image ----------------
__global__ __launch_bounds__(256) void conv_kernel(const float* __restrict__ x,
        const float* __restrict__ w1, const float* __restrict__ b1,
        const float* __restrict__ w2, const float* __restrict__ b2,
        const float* __restrict__ w3, const float* __restrict__ b3,
        float* __restrict__ out) {
    __shared__ float arena[16384];
    const int t = threadIdx.x;
    const size_t img = blockIdx.x;

    float* s_out1 = arena;
    float* s_w1   = arena + 1936;
    float* s_b1   = arena + 3232;
    float* s_img  = arena + 3248;
    const float* xi = x + img * 9801;
    for (int i = t; i < 9801; i += 256) s_img[i] = xi[i] * (1.0f / 255.0f);
    for (int i = t; i < 1296; i += 256) s_w1[i] = w1[i];
    if (t < 16) s_b1[t] = b1[t];
    __syncthreads();

    if (t < 176) {
        int c = t / 11, i = t - c * 11;
        float accr[11];
        #pragma unroll
        for (int j = 0; j < 11; ++j) accr[j] = s_b1[c];
        for (int ky = 0; ky < 9; ++ky) {
            const float* irow = s_img + (i * 9 + ky) * 99;
            const float* wrow = s_w1 + c * 81 + ky * 9;
            for (int kx = 0; kx < 9; ++kx) {
                float wv = wrow[kx];
                #pragma unroll
                for (int j = 0; j < 11; ++j) accr[j] += wv * irow[j * 9 + kx];
            }
        }
        #pragma unroll
        for (int j = 0; j < 11; ++j) s_out1[c * 121 + i * 11 + j] = fmaxf(accr[j], 0.0f);
    }
    __syncthreads();

    float* s_w2   = arena + 1936;
    float* s_b2   = arena + 6544;
    float* s_out2 = arena + 13792;
    for (int i = t; i < 4608; i += 256) s_w2[i] = w2[i];
    if (t < 32) s_b2[t] = b2[t];
    __syncthreads();

    for (int rr = 0; rr < 2; ++rr) {
        int task = rr * 256 + t;
        if (task < 288) {
            int c = task / 9, i = task - c * 9;
            float accr[9];
            #pragma unroll
            for (int j = 0; j < 9; ++j) accr[j] = s_b2[c];
            for (int ic = 0; ic < 16; ++ic) {
                const float* ibase = s_out1 + ic * 121 + i * 11;
                const float* wbase = s_w2 + (c * 16 + ic) * 9;
                #pragma unroll
                for (int ky = 0; ky < 3; ++ky) {
                    const float* irow = ibase + ky * 11;
                    #pragma unroll
                    for (int kx = 0; kx < 3; ++kx) {
                        float wv = wbase[ky * 3 + kx];
                        #pragma unroll
                        for (int j = 0; j < 9; ++j) accr[j] += wv * irow[j + kx];
                    }
                }
            }
            #pragma unroll
            for (int j = 0; j < 9; ++j) s_out2[c * 81 + i * 9 + j] = fmaxf(accr[j], 0.0f);
        }
    }
    __syncthreads();

    float* s_w3   = arena;
    float* s_b3   = arena + 9216;
    float* s_out3 = arena + 9248;
    for (int i = t; i < 9216; i += 256) s_w3[i] = w3[i];
    if (t < 32) s_b3[t] = b3[t];
    __syncthreads();

    if (t < 224) {
        int c = t / 7, i = t - c * 7;
        float accr[7];
        #pragma unroll
        for (int j = 0; j < 7; ++j) accr[j] = s_b3[c];
        for (int ic = 0; ic < 32; ++ic) {
            const float* ibase = s_out2 + ic * 81 + i * 9;
            const float* wbase = s_w3 + (c * 32 + ic) * 9;
            #pragma unroll
            for (int ky = 0; ky < 3; ++ky) {
                const float* irow = ibase + ky * 9;
                #pragma unroll
                for (int kx = 0; kx < 3; ++kx) {
                    float wv = wbase[ky * 3 + kx];
                    #pragma unroll
                    for (int j = 0; j < 7; ++j) accr[j] += wv * irow[j + kx];
                }
            }
        }
        #pragma unroll
        for (int j = 0; j < 7; ++j) s_out3[c * 49 + i * 7 + j] = fmaxf(accr[j], 0.0f);
    }
    __syncthreads();
    float* og = out + img * 1568;
    for (int i = t; i < 1568; i += 256) og[i] = s_out3[i];
}

// ---------------- generic tiled GEMM ----------------
template <bool RELU>
__global__ __launch_bounds__(64) void gemm64(const float* __restrict__ A, const float* __restrict__ W,
                                             const float* __restrict__ bias, float* __restrict__ C,
                                             int M, int N, int K) {
    __shared__ float At[32][68];
    __shared__ float Wt[32][68];
    const int m0 = blockIdx.x * 64, n0 = blockIdx.y * 64;
    const int t = threadIdx.x;
    const int tx = t & 7, ty = t >> 3;
    float acc[8][8] = {};
    for (int kc = 0; kc < K; kc += 32) {
        #pragma unroll
        for (int i = 0; i < 8; ++i) {
            int e = t + i * 64;
            int row = e >> 3, c4 = (e & 7) * 4;
            float4 v = *(const float4*)&A[(size_t)(m0 + row) * K + kc + c4];
            At[c4 + 0][row] = v.x; At[c4 + 1][row] = v.y; At[c4 + 2][row] = v.z; At[c4 + 3][row] = v.w;
            int n = n0 + row;
            float4 wv = make_float4(0.f, 0.f, 0.f, 0.f);
            if (n < N) wv = *(const float4*)&W[(size_t)n * K + kc + c4];
            Wt[c4 + 0][row] = wv.x; Wt[c4 + 1][row] = wv.y; Wt[c4 + 2][row] = wv.z; Wt[c4 + 3][row] = wv.w;
        }
        __syncthreads();
        #pragma unroll
        for (int kk = 0; kk < 32; ++kk) {
            float4 a0 = *(const float4*)&At[kk][ty * 8];
            float4 a1 = *(const float4*)&At[kk][ty * 8 + 4];
            float4 b0 = *(const float4*)&Wt[kk][tx * 8];
            float4 b1 = *(const float4*)&Wt[kk][tx * 8 + 4];
            float a[8] = {a0.x, a0.y, a0.z, a0.w, a1.x, a1.y, a1.z, a1.w};
            float b[8] = {b0.x, b0.y, b0.z, b0.w, b1.x, b1.y, b1.z, b1.w};
            #pragma unroll
            for (int i = 0; i < 8; ++i)
                #pragma unroll
                for (int j = 0; j < 8; ++j) acc[i][j] += a[i] * b[j];
        }
        __syncthreads();
    }
    #pragma unroll
    for (int i = 0; i < 8; ++i) {
        int m = m0 + ty * 8 + i;
        #pragma unroll
        for (int j = 0; j < 8; ++j) {
            int n = n0 + tx * 8 + j;
            if (n < N) {
                float v = acc[i][j] + bias[n];
                if (RELU) v = fmaxf(v, 0.0f);
                C[(size_t)m * N + n] = v;
            }
        }
    }
}

// ---------------- embedding ----------------
__global__ void embed_kernel(const int* __restrict__ lang, const float* __restrict__ emb,
                             float* __restrict__ out) {
    int g = blockIdx.x * 256 + threadIdx.x;
    if (g < TBTOT * 32) { int r = g >> 5, c = g & 31; out[g] = emb[lang[r] * 32 + c]; }
}

// ---------------- concat ----------------
__global__ void concat_kernel(const float* __restrict__ img_h, const float* __restrict__ lang_h,
                              float* __restrict__ out) {
    int r = blockIdx.x, c = threadIdx.x;
    out[r * 288 + c] = (c < 256) ? img_h[r * 256 + c] : lang_h[r * 32 + (c - 256)];
}

// ---------------- persistent MFMA LSTM scan: REGISTER-RESIDENT WEIGHTS ----------------
// 512 threads = 8 waves; wave (q=wid>>1, kh=wid&1) owns gate q, k-slices ks=2*w+kh.
// Whh hi/lo fragments live in VGPRs for the whole scan (immune to the barrier's
// cache invalidate). Per step only h streams (LDS-staged, 2-deep reg prefetch).
// Gate partials from the kh pair summed via LDS. One cell per thread in epilogue.
template <int H, bool PER_ENV>
__global__ __launch_bounds__(512, 2) void lstm_mfma_kernel(
        const float* __restrict__ xw,      // [T*B][4H]
        const short* __restrict__ wf_hi,
        const short* __restrict__ wf_lo,
        const float* __restrict__ done,
        const float* __restrict__ h0, const float* __restrict__ c0,
        short* __restrict__ hbuf_hi,       // [2][B][H]
        short* __restrict__ hbuf_lo,
        float* __restrict__ hs,            // [T*B][H]
        unsigned* __restrict__ bar_base, unsigned sub_target) {
    constexpr int NKS2 = H / 64;           // k-slices per wave (stride-2 interleave)
    constexpr int NCH  = H / 256;          // 256-col chunks
    constexpr int njt  = H / 16, nks = H / 32;
    __shared__ bf16x8 lsA[2][1024];        // staged h chunk [hi/lo][32 rows x 32 segs]
    __shared__ float  gbuf[8][32][16];     // per-wave gate partials
    const int t    = threadIdx.x;
    const int lane = t & 63;
    const int wid  = t >> 6;               // 0..7
    const int q    = wid >> 1, kh = wid & 1;
    const int jt   = blockIdx.x, j0 = jt * 16;
    const int b0   = blockIdx.y * 32;
    const int row_c = t >> 4;              // epilogue cell row 0..31
    const int jl   = t & 15;
    const int jg   = j0 + jl;
    unsigned* gbar = bar_base + blockIdx.y * 160;
    const unsigned sub = blockIdx.x & 7u;

    // ---- weight prologue: fragments into registers, kept for all 64 steps ----
    bf16x8 wreg_h[NKS2], wreg_l[NKS2];
    {
        const bf16x8* bfh = (const bf16x8*)wf_hi + (size_t)(q * njt + jt) * nks * 64;
        const bf16x8* bfl = (const bf16x8*)wf_lo + (size_t)(q * njt + jt) * nks * 64;
        #pragma unroll
        for (int w = 0; w < NKS2; ++w) {
            int ks = 2 * w + kh;
            wreg_h[w] = bfh[(size_t)ks * 64 + lane];
            wreg_l[w] = bfl[(size_t)ks * 64 + lane];
        }
    }

    const int bgl = b0 + row_c;
    float c_reg = c0[(size_t)bgl * H + jg];
    {
        float v = h0[(size_t)bgl * H + jg];
        short a = f32_to_bf16_rne(v);
        short l = f32_to_bf16_rne(v - bf16s_to_f32(a));
        hbuf_hi[(size_t)bgl * H + jg] = a;
        hbuf_lo[(size_t)bgl * H + jg] = l;
    }
    unsigned bar = 1;
    gridbar2(gbar, bar, sub, sub_target); ++bar;

    const bf16x8 zero8 = {0, 0, 0, 0, 0, 0, 0, 0};
    int cur = 0;
    for (int st = 0; st < T_STEPS; ++st) {
        const short* hsh = hbuf_hi + (size_t)cur * (BATCH * H);
        const short* hsl = hbuf_lo + (size_t)cur * (BATCH * H);
        const float m_step = PER_ENV ? 0.0f : (1.0f - done[st]);

        // xw prefetch for this thread's cell (independent of h)
        float xg[4];
        {
            const float* xr = xw + (size_t)(st * BATCH + bgl) * (4 * H);
            #pragma unroll
            for (int g4 = 0; g4 < 4; ++g4) xg[g4] = xr[g4 * H + jg];
        }
        const float m_c = PER_ENV ? (1.0f - done[st * BATCH + bgl]) : m_step;

        f32x4 acc0 = {0.f, 0.f, 0.f, 0.f};
        f32x4 acc1 = {0.f, 0.f, 0.f, 0.f};

        bf16x8 rA[2][2], rB[2][2];
        auto loadC = [&](bf16x8 (&r)[2][2], int c) {
            #pragma unroll
            for (int i = 0; i < 2; ++i) {
                int idx = i * 512 + t;
                int row = idx >> 5, seg = idx & 31;
                size_t base = (size_t)(b0 + row) * H + c * 256 + seg * 8;
                r[0][i] = *(const bf16x8*)&hsh[base];
                r[1][i] = *(const bf16x8*)&hsl[base];
            }
        };
        auto writeC = [&](bf16x8 (&r)[2][2]) {
            #pragma unroll
            for (int i = 0; i < 2; ++i) {
                int idx = i * 512 + t;
                int row = idx >> 5, seg = idx & 31;
                float m = PER_ENV ? (1.0f - done[st * BATCH + b0 + row]) : m_step;
                int slot = seg * 32 + ((row ^ seg) & 31);
                bf16x8 vh = r[0][i], vl = r[1][i];
                if (m == 0.0f) { vh = zero8; vl = zero8; }
                lsA[0][slot] = vh;
                lsA[1][slot] = vl;
            }
        };
        auto mfmaC = [&](int c) {
            #pragma unroll
            for (int w = 0; w < NKS2; ++w) {
                int rel = 2 * w + kh - c * 8;   // k-slice position within chunk
                if (rel >= 0 && rel < 8) {      // wave-uniform test
                    int kgrp = rel * 4 + (lane >> 4);
                    int r0 = lane & 15, r1 = r0 + 16;
                    bf16x8 a0h = lsA[0][kgrp * 32 + ((r0 ^ kgrp) & 31)];
                    bf16x8 a0l = lsA[1][kgrp * 32 + ((r0 ^ kgrp) & 31)];
                    bf16x8 a1h = lsA[0][kgrp * 32 + ((r1 ^ kgrp) & 31)];
                    bf16x8 a1l = lsA[1][kgrp * 32 + ((r1 ^ kgrp) & 31)];
                    acc0 = __builtin_amdgcn_mfma_f32_16x16x32_bf16(a0h, wreg_h[w], acc0, 0, 0, 0);
                    acc1 = __builtin_amdgcn_mfma_f32_16x16x32_bf16(a1h, wreg_h[w], acc1, 0, 0, 0);
                    acc0 = __builtin_amdgcn_mfma_f32_16x16x32_bf16(a0h, wreg_l[w], acc0, 0, 0, 0);
                    acc1 = __builtin_amdgcn_mfma_f32_16x16x32_bf16(a1h, wreg_l[w], acc1, 0, 0, 0);
                    acc0 = __builtin_amdgcn_mfma_f32_16x16x32_bf16(a0l, wreg_h[w], acc0, 0, 0, 0);
                    acc1 = __builtin_amdgcn_mfma_f32_16x16x32_bf16(a1l, wreg_h[w], acc1, 0, 0, 0);
                }
            }
        };

        loadC(rA, 0);
        #pragma unroll
        for (int c = 0; c < NCH; ++c) {
            if (c + 1 < NCH) {
                if ((c + 1) & 1) loadC(rB, c + 1); else loadC(rA, c + 1);
            }
            if (c & 1) writeC(rB); else writeC(rA);
            __syncthreads();
            mfmaC(c);
            __syncthreads();
        }

        // gate partial exchange (C/D layout: col=lane&15, row=(lane>>4)*4+r)
        #pragma unroll
        for (int r = 0; r < 4; ++r) {
            gbuf[wid][(lane >> 4) * 4 + r][lane & 15]      = acc0[r];
            gbuf[wid][16 + (lane >> 4) * 4 + r][lane & 15] = acc1[r];
        }
        __syncthreads();

        // epilogue: one cell per thread; gate g = gbuf[2g] + gbuf[2g+1]
        float gi = gbuf[0][row_c][jl] + gbuf[1][row_c][jl] + xg[0];
        float gf = gbuf[2][row_c][jl] + gbuf[3][row_c][jl] + xg[1];
        float gg = gbuf[4][row_c][jl] + gbuf[5][row_c][jl] + xg[2];
        float go = gbuf[6][row_c][jl] + gbuf[7][row_c][jl] + xg[3];
        float cc = fast_sigm(gf) * (c_reg * m_c) + fast_sigm(gi) * fast_tanh(gg);
        float hh = fast_sigm(go) * fast_tanh(cc);
        c_reg = cc;
        hs[(size_t)(st * BATCH + bgl) * H + jg] = hh;
        short hhi = f32_to_bf16_rne(hh);
        short hlo = f32_to_bf16_rne(hh - bf16s_to_f32(hhi));
        size_t ho = (size_t)(cur ^ 1) * (BATCH * H) + (size_t)bgl * H + jg;
        hbuf_hi[ho] = hhi;
        hbuf_lo[ho] = hlo;

        gridbar2(gbar, bar, sub, sub_target); ++bar;
        cur ^= 1;
    }
}

extern "C" void kernel_launch(void* const* d_in, const int* in_sizes, int n_in,
                              void* d_out, int out_size, void* d_ws, size_t ws_size,
                              hipStream_t stream) {
    const float* x_img    = (const float*)d_in[0];
    const int*   x_lang   = (const int*)d_in[1];
    const float* done     = (const float*)d_in[2];
    const float* enc_h0   = (const float*)d_in[3];
    const float* enc_c0   = (const float*)d_in[4];
    const float* mem_h0   = (const float*)d_in[5];
    const float* mem_c0   = (const float*)d_in[6];
    const float* emb      = (const float*)d_in[7];
    const float* conv1_w  = (const float*)d_in[8];
    const float* conv1_b  = (const float*)d_in[9];
    const float* conv2_w  = (const float*)d_in[10];
    const float* conv2_b  = (const float*)d_in[11];
    const float* conv3_w  = (const float*)d_in[12];
    const float* conv3_b  = (const float*)d_in[13];
    const float* fc_w     = (const float*)d_in[14];
    const float* fc_b     = (const float*)d_in[15];
    const float* enc_Wih  = (const float*)d_in[16];
    const float* enc_Whh  = (const float*)d_in[17];
    const float* enc_bih  = (const float*)d_in[18];
    const float* enc_bhh  = (const float*)d_in[19];
    const float* lemb_w   = (const float*)d_in[20];
    const float* lemb_b   = (const float*)d_in[21];
    const float* mem_Wih  = (const float*)d_in[22];
    const float* mem_Whh  = (const float*)d_in[23];
    const float* mem_bih  = (const float*)d_in[24];
    const float* mem_bhh  = (const float*)d_in[25];
    const float* actor_w  = (const float*)d_in[26];
    const float* actor_b  = (const float*)d_in[27];
    const float* critic_w = (const float*)d_in[28];
    const float* critic_b = (const float*)d_in[29];

    float* ws = (float*)d_ws;
    float* conv3_flat = ws + OFF_CONV3;
    short* mem_wf_hi  = (short*)(ws + OFF_MWFHI);
    short* mem_wf_lo  = (short*)(ws + OFF_MWFLO);
    short* enc_wf_hi  = (short*)(ws + OFF_EWFHI);
    short* enc_wf_lo  = (short*)(ws + OFF_EWFLO);
    short* hbm_hi     = (short*)(ws + OFF_HBMHI);
    short* hbm_lo     = (short*)(ws + OFF_HBMLO);
    short* hbe_hi     = (short*)(ws + OFF_HBEHI);
    short* hbe_lo     = (short*)(ws + OFF_HBELO);
    float* img_hidden = ws + OFF_IMGH;
    float* lang_in    = ws + OFF_LANGIN;
    float* enc_xW     = ws + OFF_ENCXW;
    float* enc_hs     = ws + OFF_ENCHS;
    float* lang_h     = ws + OFF_LANGH;
    float* hidden     = ws + OFF_HIDDEN;
    float* mem_xW     = ws + OFF_MEMXW;
    float* mem_hs     = ws + OFF_MEMHS;
    float* enc_bc     = ws + OFF_ENCBC;
    float* mem_bc     = ws + OFF_MEMBC;
    float* head_w     = ws + OFF_HEADW;
    float* head_b     = ws + OFF_HEADB;
    unsigned* bars    = (unsigned*)(ws + OFF_BARS);

    prep_kernel<<<64, 256, 0, stream>>>(enc_bih, enc_bhh, mem_bih, mem_bhh,
                                        actor_w, actor_b, critic_w, critic_b,
                                        enc_bc, mem_bc, head_w, head_b, bars);
    conv_kernel<<<TBTOT, 256, 0, stream>>>(x_img, conv1_w, conv1_b, conv2_w, conv2_b,
                                           conv3_w, conv3_b, conv3_flat);
    gemm64<true><<<dim3(128, 4), 64, 0, stream>>>(conv3_flat, fc_w, fc_b, img_hidden, TBTOT, 256, 1568);
    // conv3 region dead from here; build LSTM split-weight fragments in it
    split_frag_kernel<<<65536, 256, 0, stream>>>(mem_Whh, mem_wf_hi, mem_wf_lo, 1024);
    split_frag_kernel<<<4096, 256, 0, stream>>>(enc_Whh, enc_wf_hi, enc_wf_lo, 256);
    embed_kernel<<<1024, 256, 0, stream>>>(x_lang, emb, lang_in);
    gemm64<false><<<dim3(128, 16), 64, 0, stream>>>(lang_in, enc_Wih, enc_bc, enc_xW, TBTOT, 1024, 32);
    lstm_mfma_kernel<256, false><<<dim3(16, 4), 512, 0, stream>>>(
        enc_xW, enc_wf_hi, enc_wf_lo, done, enc_h0, enc_c0, hbe_hi, hbe_lo, enc_hs,
        bars + 0, 2u);
    gemm64<true><<<dim3(128, 1), 64, 0, stream>>>(enc_hs, lemb_w, lemb_b, lang_h, TBTOT, 32, 256);
    concat_kernel<<<TBTOT, 288, 0, stream>>>(img_hidden, lang_h, hidden);
    gemm64<false><<<dim3(128, 64), 64, 0, stream>>>(hidden, mem_Wih, mem_bc, mem_xW, TBTOT, 4096, 288);
    lstm_mfma_kernel<1024, true><<<dim3(64, 4), 512, 0, stream>>>(
        mem_xW, mem_wf_hi, mem_wf_lo, done, mem_h0, mem_c0, hbm_hi, hbm_lo, mem_hs,
        bars + 640, 8u);
    gemm64<false><<<dim3(128, 1), 64, 0, stream>>>(mem_hs, head_w, head_b, (float*)d_out, TBTOT, 16, 1024);
}

// Round 8
// 3551.380 us; speedup vs baseline: 1.1698x; 1.0016x over previous
//
#include <hip/hip_runtime.h>
#include <math.h>

#define T_STEPS 64
#define BATCH   128
#define TBTOT   8192

typedef __attribute__((ext_vector_type(8))) short bf16x8;
typedef __attribute__((ext_vector_type(4))) float f32x4;

// ---------------- workspace layout (float offsets) ----------------
static const size_t OFF_CONV3  = 0;              // [8192][1568] f32 (phase 1)
static const size_t OFF_MWFHI  = 0;              // [4096*1024] bf16  (phase 2)
static const size_t OFF_MWFLO  = 2097152;        // [4096*1024] bf16
static const size_t OFF_EWFHI  = 4194304;        // [1024*256] bf16
static const size_t OFF_EWFLO  = 4325376;        // [1024*256] bf16
static const size_t OFF_HBMHI  = 4456448;        // [2][128][1024] bf16
static const size_t OFF_HBMLO  = 4587520;        // [2][128][1024] bf16
static const size_t OFF_HBEHI  = 4718592;        // [2][128][256] bf16
static const size_t OFF_HBELO  = 4734976;        // [2][128][256] bf16
static const size_t OFF_IMGH   = 12845056;       // [8192][256]
static const size_t OFF_LANGIN = 14942208;       // [8192][32]
static const size_t OFF_ENCXW  = 15204352;       // [8192][1024]
static const size_t OFF_ENCHS  = 23592960;       // [8192][256]
static const size_t OFF_LANGH  = 25690112;       // [8192][32]
static const size_t OFF_HIDDEN = 25952256;       // [8192][288]
static const size_t OFF_MEMXW  = 28311552;       // [8192][4096]
static const size_t OFF_MEMHS  = 61865984;       // [8192][1024]
static const size_t OFF_ENCBC  = 70582272;       // [1024]
static const size_t OFF_MEMBC  = 70583296;       // [4096]
static const size_t OFF_HEADW  = 70587392;       // [16][1024]
static const size_t OFF_HEADB  = 70603776;       // [16]
static const size_t OFF_BARS   = 70603792;       // 1280 uints (per-group barrier counters)

__device__ __forceinline__ float fast_sigm(float x) { return 1.0f / (1.0f + __expf(-x)); }
__device__ __forceinline__ float fast_tanh(float x) { return 2.0f / (1.0f + __expf(-2.0f * x)) - 1.0f; }

__device__ __forceinline__ short f32_to_bf16_rne(float x) {
    unsigned u = __float_as_uint(x);
    unsigned r = (u + 0x7fffu + ((u >> 16) & 1u)) >> 16;
    return (short)r;
}
__device__ __forceinline__ float bf16s_to_f32(short s) {
    return __uint_as_float(((unsigned)(unsigned short)s) << 16);
}

// -------- per-group hierarchical barrier, relaxed spin + single acquire fence --------
__device__ __forceinline__ void gridbar2(unsigned* g, unsigned round,
                                         unsigned sub, unsigned sub_target) {
    __syncthreads();
    if (threadIdx.x == 0) {
        __threadfence();
        unsigned old = __hip_atomic_fetch_add(&g[sub * 16], 1u,
                                              __ATOMIC_RELEASE, __HIP_MEMORY_SCOPE_AGENT);
        if (old + 1u == sub_target * round) {
            __hip_atomic_fetch_add(&g[128], 1u,
                                   __ATOMIC_RELEASE, __HIP_MEMORY_SCOPE_AGENT);
        }
        while (__hip_atomic_load(&g[128], __ATOMIC_RELAXED,
                                 __HIP_MEMORY_SCOPE_AGENT) < 8u * round) {
            __builtin_amdgcn_s_sleep(2);
        }
        __builtin_amdgcn_fence(__ATOMIC_ACQUIRE, "agent");
    }
    __syncthreads();
}

// ---------------- prep ----------------
__global__ void prep_kernel(const float* __restrict__ enc_bih, const float* __restrict__ enc_bhh,
                            const float* __restrict__ mem_bih, const float* __restrict__ mem_bhh,
                            const float* __restrict__ actor_w, const float* __restrict__ actor_b,
                            const float* __restrict__ critic_w, const float* __restrict__ critic_b,
                            float* __restrict__ enc_bc, float* __restrict__ mem_bc,
                            float* __restrict__ head_w, float* __restrict__ head_b,
                            unsigned* __restrict__ bars) {
    int g = blockIdx.x * 256 + threadIdx.x;
    if (g < 1024)  enc_bc[g] = enc_bih[g] + enc_bhh[g];
    if (g < 4096)  mem_bc[g] = mem_bih[g] + mem_bhh[g];
    if (g < 16384) { int j = g >> 10, k = g & 1023; head_w[g] = (j < 15) ? actor_w[j * 1024 + k] : critic_w[k]; }
    if (g < 16)    head_b[g] = (g < 15) ? actor_b[g] : critic_b[0];
    if (g < 1280)  bars[g] = 0u;
}

// ---------------- split Whh into MFMA-fragment-ordered bf16 hi/lo ----------------
__global__ void split_frag_kernel(const float* __restrict__ W, short* __restrict__ hi,
                                  short* __restrict__ lo, int H) {
    size_t f = (size_t)blockIdx.x * 256 + threadIdx.x;
    size_t total = (size_t)4 * H * H;
    if (f >= total) return;
    int e    = (int)(f & 7);
    int lane = (int)((f >> 3) & 63);
    size_t rest = f >> 9;
    int nks = H >> 5;
    int ks  = (int)(rest % nks);
    int qjt = (int)(rest / nks);
    int njt = H >> 4;
    int qq = qjt / njt, jt = qjt - qq * njt;
    int n = qq * H + jt * 16 + (lane & 15);
    int k = ks * 32 + (lane >> 4) * 8 + e;
    float w = W[(size_t)n * H + k];
    short a = f32_to_bf16_rne(w);
    short b = f32_to_bf16_rne(w - bf16s_to_f32(a));
    hi[f] = a; lo[f] = b;
}

// ---------------- fused conv stack, one block per image ----------------
__global__ __launch_bounds__(256) void conv_kernel(const float* __restrict__ x,
        const float* __restrict__ w1, const float* __restrict__ b1,
        const float* __restrict__ w2, const float* __restrict__ b2,
        const float* __restrict__ w3, const float* __restrict__ b3,
        float* __restrict__ out) {
    __shared__ float arena[16384];
    const int t = threadIdx.x;
    const size_t img = blockIdx.x;

    float* s_out1 = arena;
    float* s_w1   = arena + 1936;
    float* s_b1   = arena + 3232;
    float* s_img  = arena + 3248;
    const float* xi = x + img * 9801;
    for (int i = t; i < 9801; i += 256) s_img[i] = xi[i] * (1.0f / 255.0f);
    for (int i = t; i < 1296; i += 256) s_w1[i] = w1[i];
    if (t < 16) s_b1[t] = b1[t];
    __syncthreads();

    if (t < 176) {
        int c = t / 11, i = t - c * 11;
        float accr[11];
        #pragma unroll
        for (int j = 0; j < 11; ++j) accr[j] = s_b1[c];
        for (int ky = 0; ky < 9; ++ky) {
            const float* irow = s_img + (i * 9 + ky) * 99;
            const float* wrow = s_w1 + c * 81 + ky * 9;
            for (int kx = 0; kx < 9; ++kx) {
                float wv = wrow[kx];
                #pragma unroll
                for (int j = 0; j < 11; ++j) accr[j] += wv * irow[j * 9 + kx];
            }
        }
        #pragma unroll
        for (int j = 0; j < 11; ++j) s_out1[c * 121 + i * 11 + j] = fmaxf(accr[j], 0.0f);
    }
    __syncthreads();

    float* s_w2   = arena + 1936;
    float* s_b2   = arena + 6544;
    float* s_out2 = arena + 13792;
    for (int i = t; i < 4608; i += 256) s_w2[i] = w2[i];
    if (t < 32) s_b2[t] = b2[t];
    __syncthreads();

    for (int rr = 0; rr < 2; ++rr) {
        int task = rr * 256 + t;
        if (task < 288) {
            int c = task / 9, i = task - c * 9;
            float accr[9];
            #pragma unroll
            for (int j = 0; j < 9; ++j) accr[j] = s_b2[c];
            for (int ic = 0; ic < 16; ++ic) {
                const float* ibase = s_out1 + ic * 121 + i * 11;
                const float* wbase = s_w2 + (c * 16 + ic) * 9;
                #pragma unroll
                for (int ky = 0; ky < 3; ++ky) {
                    const float* irow = ibase + ky * 11;
                    #pragma unroll
                    for (int kx = 0; kx < 3; ++kx) {
                        float wv = wbase[ky * 3 + kx];
                        #pragma unroll
                        for (int j = 0; j < 9; ++j) accr[j] += wv * irow[j + kx];
                    }
                }
            }
            #pragma unroll
            for (int j = 0; j < 9; ++j) s_out2[c * 81 + i * 9 + j] = fmaxf(accr[j], 0.0f);
        }
    }
    __syncthreads();

    float* s_w3   = arena;
    float* s_b3   = arena + 9216;
    float* s_out3 = arena + 9248;
    for (int i = t; i < 9216; i += 256) s_w3[i] = w3[i];
    if (t < 32) s_b3[t] = b3[t];
    __syncthreads();

    if (t < 224) {
        int c = t / 7, i = t - c * 7;
        float accr[7];
        #pragma unroll
        for (int j = 0; j < 7; ++j) accr[j] = s_b3[c];
        for (int ic = 0; ic < 32; ++ic) {
            const float* ibase = s_out2 + ic * 81 + i * 9;
            const float* wbase = s_w3 + (c * 32 + ic) * 9;
            #pragma unroll
            for (int ky = 0; ky < 3; ++ky) {
                const float* irow = ibase + ky * 9;
                #pragma unroll
                for (int kx = 0; kx < 3; ++kx) {
                    float wv = wbase[ky * 3 + kx];
                    #pragma unroll
                    for (int j = 0; j < 7; ++j) accr[j] += wv * irow[j + kx];
                }
            }
        }
        #pragma unroll
        for (int j = 0; j < 7; ++j) s_out3[c * 49 + i * 7 + j] = fmaxf(accr[j], 0.0f);
    }
    __syncthreads();
    float* og = out + img * 1568;
    for (int i = t; i < 1568; i += 256) og[i] = s_out3[i];
}

// ---------------- generic tiled GEMM ----------------
template <bool RELU>
__global__ __launch_bounds__(64) void gemm64(const float* __restrict__ A, const float* __restrict__ W,
                                             const float* __restrict__ bias, float* __restrict__ C,
                                             int M, int N, int K) {
    __shared__ float At[32][68];
    __shared__ float Wt[32][68];
    const int m0 = blockIdx.x * 64, n0 = blockIdx.y * 64;
    const int t = threadIdx.x;
    const int tx = t & 7, ty = t >> 3;
    float acc[8][8] = {};
    for (int kc = 0; kc < K; kc += 32) {
        #pragma unroll
        for (int i = 0; i < 8; ++i) {
            int e = t + i * 64;
            int row = e >> 3, c4 = (e & 7) * 4;
            float4 v = *(const float4*)&A[(size_t)(m0 + row) * K + kc + c4];
            At[c4 + 0][row] = v.x; At[c4 + 1][row] = v.y; At[c4 + 2][row] = v.z; At[c4 + 3][row] = v.w;
            int n = n0 + row;
            float4 wv = make_float4(0.f, 0.f, 0.f, 0.f);
            if (n < N) wv = *(const float4*)&W[(size_t)n * K + kc + c4];
            Wt[c4 + 0][row] = wv.x; Wt[c4 + 1][row] = wv.y; Wt[c4 + 2][row] = wv.z; Wt[c4 + 3][row] = wv.w;
        }
        __syncthreads();
        #pragma unroll
        for (int kk = 0; kk < 32; ++kk) {
            float4 a0 = *(const float4*)&At[kk][ty * 8];
            float4 a1 = *(const float4*)&At[kk][ty * 8 + 4];
            float4 b0 = *(const float4*)&Wt[kk][tx * 8];
            float4 b1 = *(const float4*)&Wt[kk][tx * 8 + 4];
            float a[8] = {a0.x, a0.y, a0.z, a0.w, a1.x, a1.y, a1.z, a1.w};
            float b[8] = {b0.x, b0.y, b0.z, b0.w, b1.x, b1.y, b1.z, b1.w};
            #pragma unroll
            for (int i = 0; i < 8; ++i)
                #pragma unroll
                for (int j = 0; j < 8; ++j) acc[i][j] += a[i] * b[j];
        }
        __syncthreads();
    }
    #pragma unroll
    for (int i = 0; i < 8; ++i) {
        int m = m0 + ty * 8 + i;
        #pragma unroll
        for (int j = 0; j < 8; ++j) {
            int n = n0 + tx * 8 + j;
            if (n < N) {
                float v = acc[i][j] + bias[n];
                if (RELU) v = fmaxf(v, 0.0f);
                C[(size_t)m * N + n] = v;
            }
        }
    }
}

// ---------------- embedding ----------------
__global__ void embed_kernel(const int* __restrict__ lang, const float* __restrict__ emb,
                             float* __restrict__ out) {
    int g = blockIdx.x * 256 + threadIdx.x;
    if (g < TBTOT * 32) { int r = g >> 5, c = g & 31; out[g] = emb[lang[r] * 32 + c]; }
}

// ---------------- concat ----------------
__global__ void concat_kernel(const float* __restrict__ img_h, const float* __restrict__ lang_h,
                              float* __restrict__ out) {
    int r = blockIdx.x, c = threadIdx.x;
    out[r * 288 + c] = (c < 256) ? img_h[r * 256 + c] : lang_h[r * 32 + (c - 256)];
}

// ---------------- persistent MFMA LSTM scan: PINNED register-resident weights ----------------
// 512 threads = 8 waves; wave (q=wid>>1, kh=wid&1) owns gate q, k-slices ks=2*w+kh.
// Whh hi/lo fragments are loaded once and PINNED in VGPRs via asm (compiler cannot
// rematerialize the loads), making them immune to the barrier's cache invalidate.
template <int H, bool PER_ENV>
__global__ __launch_bounds__(512, 2) void lstm_mfma_kernel(
        const float* __restrict__ xw,      // [T*B][4H]
        const short* __restrict__ wf_hi,
        const short* __restrict__ wf_lo,
        const float* __restrict__ done,
        const float* __restrict__ h0, const float* __restrict__ c0,
        short* __restrict__ hbuf_hi,       // [2][B][H]
        short* __restrict__ hbuf_lo,
        float* __restrict__ hs,            // [T*B][H]
        unsigned* __restrict__ bar_base, unsigned sub_target) {
    constexpr int NKS2 = H / 64;           // k-slices per wave (stride-2 interleave)
    constexpr int NCH  = H / 256;          // 256-col chunks
    constexpr int njt  = H / 16, nks = H / 32;
    __shared__ bf16x8 lsA[2][1024];        // staged h chunk [hi/lo][32 rows x 32 segs]
    __shared__ float  gbuf[8][32][16];     // per-wave gate partials
    const int t    = threadIdx.x;
    const int lane = t & 63;
    const int wid  = t >> 6;               // 0..7
    const int q    = wid >> 1, kh = wid & 1;
    const int jt   = blockIdx.x, j0 = jt * 16;
    const int b0   = blockIdx.y * 32;
    const int row_c = t >> 4;              // epilogue cell row 0..31
    const int jl   = t & 15;
    const int jg   = j0 + jl;
    unsigned* gbar = bar_base + blockIdx.y * 160;
    const unsigned sub = blockIdx.x & 7u;

    // ---- weight prologue: fragments into registers, PINNED for all 64 steps ----
    bf16x8 wreg_h[NKS2], wreg_l[NKS2];
    {
        const bf16x8* bfh = (const bf16x8*)wf_hi + (size_t)(q * njt + jt) * nks * 64;
        const bf16x8* bfl = (const bf16x8*)wf_lo + (size_t)(q * njt + jt) * nks * 64;
        #pragma unroll
        for (int w = 0; w < NKS2; ++w) {
            int ks = 2 * w + kh;
            wreg_h[w] = bfh[(size_t)ks * 64 + lane];
            wreg_l[w] = bfl[(size_t)ks * 64 + lane];
        }
        // Pin: make values opaque so the compiler cannot re-load them from global
        // after barrier cache-invalidates (that remat is what killed R7).
        #pragma unroll
        for (int w = 0; w < NKS2; ++w) {
            asm volatile("" : "+v"(wreg_h[w]));
            asm volatile("" : "+v"(wreg_l[w]));
        }
    }

    const int bgl = b0 + row_c;
    float c_reg = c0[(size_t)bgl * H + jg];
    {
        float v = h0[(size_t)bgl * H + jg];
        short a = f32_to_bf16_rne(v);
        short l = f32_to_bf16_rne(v - bf16s_to_f32(a));
        hbuf_hi[(size_t)bgl * H + jg] = a;
        hbuf_lo[(size_t)bgl * H + jg] = l;
    }
    unsigned bar = 1;
    gridbar2(gbar, bar, sub, sub_target); ++bar;

    const bf16x8 zero8 = {0, 0, 0, 0, 0, 0, 0, 0};
    int cur = 0;
    for (int st = 0; st < T_STEPS; ++st) {
        const short* hsh = hbuf_hi + (size_t)cur * (BATCH * H);
        const short* hsl = hbuf_lo + (size_t)cur * (BATCH * H);
        const float m_step = PER_ENV ? 0.0f : (1.0f - done[st]);

        // xw prefetch for this thread's cell (independent of h)
        float xg[4];
        {
            const float* xr = xw + (size_t)(st * BATCH + bgl) * (4 * H);
            #pragma unroll
            for (int g4 = 0; g4 < 4; ++g4) xg[g4] = xr[g4 * H + jg];
        }
        const float m_c = PER_ENV ? (1.0f - done[st * BATCH + bgl]) : m_step;

        f32x4 acc0 = {0.f, 0.f, 0.f, 0.f};
        f32x4 acc1 = {0.f, 0.f, 0.f, 0.f};

        bf16x8 rA[2][2], rB[2][2];
        auto loadC = [&](bf16x8 (&r)[2][2], int c) {
            #pragma unroll
            for (int i = 0; i < 2; ++i) {
                int idx = i * 512 + t;
                int row = idx >> 5, seg = idx & 31;
                size_t base = (size_t)(b0 + row) * H + c * 256 + seg * 8;
                r[0][i] = *(const bf16x8*)&hsh[base];
                r[1][i] = *(const bf16x8*)&hsl[base];
            }
        };
        auto writeC = [&](bf16x8 (&r)[2][2]) {
            #pragma unroll
            for (int i = 0; i < 2; ++i) {
                int idx = i * 512 + t;
                int row = idx >> 5, seg = idx & 31;
                float m = PER_ENV ? (1.0f - done[st * BATCH + b0 + row]) : m_step;
                int slot = seg * 32 + ((row ^ seg) & 31);
                bf16x8 vh = r[0][i], vl = r[1][i];
                if (m == 0.0f) { vh = zero8; vl = zero8; }
                lsA[0][slot] = vh;
                lsA[1][slot] = vl;
            }
        };
        auto mfmaC = [&](int c) {
            #pragma unroll
            for (int w = 0; w < NKS2; ++w) {
                int rel = 2 * w + kh - c * 8;   // k-slice position within chunk
                if (rel >= 0 && rel < 8) {      // wave-uniform test
                    int kgrp = rel * 4 + (lane >> 4);
                    int r0 = lane & 15, r1 = r0 + 16;
                    bf16x8 a0h = lsA[0][kgrp * 32 + ((r0 ^ kgrp) & 31)];
                    bf16x8 a0l = lsA[1][kgrp * 32 + ((r0 ^ kgrp) & 31)];
                    bf16x8 a1h = lsA[0][kgrp * 32 + ((r1 ^ kgrp) & 31)];
                    bf16x8 a1l = lsA[1][kgrp * 32 + ((r1 ^ kgrp) & 31)];
                    acc0 = __builtin_amdgcn_mfma_f32_16x16x32_bf16(a0h, wreg_h[w], acc0, 0, 0, 0);
                    acc1 = __builtin_amdgcn_mfma_f32_16x16x32_bf16(a1h, wreg_h[w], acc1, 0, 0, 0);
                    acc0 = __builtin_amdgcn_mfma_f32_16x16x32_bf16(a0h, wreg_l[w], acc0, 0, 0, 0);
                    acc1 = __builtin_amdgcn_mfma_f32_16x16x32_bf16(a1h, wreg_l[w], acc1, 0, 0, 0);
                    acc0 = __builtin_amdgcn_mfma_f32_16x16x32_bf16(a0l, wreg_h[w], acc0, 0, 0, 0);
                    acc1 = __builtin_amdgcn_mfma_f32_16x16x32_bf16(a1l, wreg_h[w], acc1, 0, 0, 0);
                }
            }
        };

        loadC(rA, 0);
        #pragma unroll
        for (int c = 0; c < NCH; ++c) {
            if (c + 1 < NCH) {
                if ((c + 1) & 1) loadC(rB, c + 1); else loadC(rA, c + 1);
            }
            if (c & 1) writeC(rB); else writeC(rA);
            __syncthreads();
            mfmaC(c);
            __syncthreads();
        }

        // gate partial exchange (C/D layout: col=lane&15, row=(lane>>4)*4+r)
        #pragma unroll
        for (int r = 0; r < 4; ++r) {
            gbuf[wid][(lane >> 4) * 4 + r][lane & 15]      = acc0[r];
            gbuf[wid][16 + (lane >> 4) * 4 + r][lane & 15] = acc1[r];
        }
        __syncthreads();

        // epilogue: one cell per thread; gate g = gbuf[2g] + gbuf[2g+1]
        float gi = gbuf[0][row_c][jl] + gbuf[1][row_c][jl] + xg[0];
        float gf = gbuf[2][row_c][jl] + gbuf[3][row_c][jl] + xg[1];
        float gg = gbuf[4][row_c][jl] + gbuf[5][row_c][jl] + xg[2];
        float go = gbuf[6][row_c][jl] + gbuf[7][row_c][jl] + xg[3];
        float cc = fast_sigm(gf) * (c_reg * m_c) + fast_sigm(gi) * fast_tanh(gg);
        float hh = fast_sigm(go) * fast_tanh(cc);
        c_reg = cc;
        hs[(size_t)(st * BATCH + bgl) * H + jg] = hh;
        short hhi = f32_to_bf16_rne(hh);
        short hlo = f32_to_bf16_rne(hh - bf16s_to_f32(hhi));
        size_t ho = (size_t)(cur ^ 1) * (BATCH * H) + (size_t)bgl * H + jg;
        hbuf_hi[ho] = hhi;
        hbuf_lo[ho] = hlo;

        gridbar2(gbar, bar, sub, sub_target); ++bar;
        cur ^= 1;
    }
}

extern "C" void kernel_launch(void* const* d_in, const int* in_sizes, int n_in,
                              void* d_out, int out_size, void* d_ws, size_t ws_size,
                              hipStream_t stream) {
    const float* x_img    = (const float*)d_in[0];
    const int*   x_lang   = (const int*)d_in[1];
    const float* done     = (const float*)d_in[2];
    const float* enc_h0   = (const float*)d_in[3];
    const float* enc_c0   = (const float*)d_in[4];
    const float* mem_h0   = (const float*)d_in[5];
    const float* mem_c0   = (const float*)d_in[6];
    const float* emb      = (const float*)d_in[7];
    const float* conv1_w  = (const float*)d_in[8];
    const float* conv1_b  = (const float*)d_in[9];
    const float* conv2_w  = (const float*)d_in[10];
    const float* conv2_b  = (const float*)d_in[11];
    const float* conv3_w  = (const float*)d_in[12];
    const float* conv3_b  = (const float*)d_in[13];
    const float* fc_w     = (const float*)d_in[14];
    const float* fc_b     = (const float*)d_in[15];
    const float* enc_Wih  = (const float*)d_in[16];
    const float* enc_Whh  = (const float*)d_in[17];
    const float* enc_bih  = (const float*)d_in[18];
    const float* enc_bhh  = (const float*)d_in[19];
    const float* lemb_w   = (const float*)d_in[20];
    const float* lemb_b   = (const float*)d_in[21];
    const float* mem_Wih  = (const float*)d_in[22];
    const float* mem_Whh  = (const float*)d_in[23];
    const float* mem_bih  = (const float*)d_in[24];
    const float* mem_bhh  = (const float*)d_in[25];
    const float* actor_w  = (const float*)d_in[26];
    const float* actor_b  = (const float*)d_in[27];
    const float* critic_w = (const float*)d_in[28];
    const float* critic_b = (const float*)d_in[29];

    float* ws = (float*)d_ws;
    float* conv3_flat = ws + OFF_CONV3;
    short* mem_wf_hi  = (short*)(ws + OFF_MWFHI);
    short* mem_wf_lo  = (short*)(ws + OFF_MWFLO);
    short* enc_wf_hi  = (short*)(ws + OFF_EWFHI);
    short* enc_wf_lo  = (short*)(ws + OFF_EWFLO);
    short* hbm_hi     = (short*)(ws + OFF_HBMHI);
    short* hbm_lo     = (short*)(ws + OFF_HBMLO);
    short* hbe_hi     = (short*)(ws + OFF_HBEHI);
    short* hbe_lo     = (short*)(ws + OFF_HBELO);
    float* img_hidden = ws + OFF_IMGH;
    float* lang_in    = ws + OFF_LANGIN;
    float* enc_xW     = ws + OFF_ENCXW;
    float* enc_hs     = ws + OFF_ENCHS;
    float* lang_h     = ws + OFF_LANGH;
    float* hidden     = ws + OFF_HIDDEN;
    float* mem_xW     = ws + OFF_MEMXW;
    float* mem_hs     = ws + OFF_MEMHS;
    float* enc_bc     = ws + OFF_ENCBC;
    float* mem_bc     = ws + OFF_MEMBC;
    float* head_w     = ws + OFF_HEADW;
    float* head_b     = ws + OFF_HEADB;
    unsigned* bars    = (unsigned*)(ws + OFF_BARS);

    prep_kernel<<<64, 256, 0, stream>>>(enc_bih, enc_bhh, mem_bih, mem_bhh,
                                        actor_w, actor_b, critic_w, critic_b,
                                        enc_bc, mem_bc, head_w, head_b, bars);
    conv_kernel<<<TBTOT, 256, 0, stream>>>(x_img, conv1_w, conv1_b, conv2_w, conv2_b,
                                           conv3_w, conv3_b, conv3_flat);
    gemm64<true><<<dim3(128, 4), 64, 0, stream>>>(conv3_flat, fc_w, fc_b, img_hidden, TBTOT, 256, 1568);
    // conv3 region dead from here; build LSTM split-weight fragments in it
    split_frag_kernel<<<65536, 256, 0, stream>>>(mem_Whh, mem_wf_hi, mem_wf_lo, 1024);
    split_frag_kernel<<<4096, 256, 0, stream>>>(enc_Whh, enc_wf_hi, enc_wf_lo, 256);
    embed_kernel<<<1024, 256, 0, stream>>>(x_lang, emb, lang_in);
    gemm64<false><<<dim3(128, 16), 64, 0, stream>>>(lang_in, enc_Wih, enc_bc, enc_xW, TBTOT, 1024, 32);
    lstm_mfma_kernel<256, false><<<dim3(16, 4), 512, 0, stream>>>(
        enc_xW, enc_wf_hi, enc_wf_lo, done, enc_h0, enc_c0, hbe_hi, hbe_lo, enc_hs,
        bars + 0, 2u);
    gemm64<true><<<dim3(128, 1), 64, 0, stream>>>(enc_hs, lemb_w, lemb_b, lang_h, TBTOT, 32, 256);
    concat_kernel<<<TBTOT, 288, 0, stream>>>(img_hidden, lang_h, hidden);
    gemm64<false><<<dim3(128, 64), 64, 0, stream>>>(hidden, mem_Wih, mem_bc, mem_xW, TBTOT, 4096, 288);
    lstm_mfma_kernel<1024, true><<<dim3(64, 4), 512, 0, stream>>>(
        mem_xW, mem_wf_hi, mem_wf_lo, done, mem_h0, mem_c0, hbm_hi, hbm_lo, mem_hs,
        bars + 640, 8u);
    gemm64<false><<<dim3(128, 1), 64, 0, stream>>>(mem_hs, head_w, head_b, (float*)d_out, TBTOT, 16, 1024);
}

// Round 9
// 2894.895 us; speedup vs baseline: 1.4351x; 1.2268x over previous
//
#include <hip/hip_runtime.h>
#include <math.h>

#define T_STEPS 64
#define BATCH   128
#define TBTOT   8192

typedef __attribute__((ext_vector_type(8))) short bf16x8;
typedef __attribute__((ext_vector_type(4))) float f32x4;

// ---------------- workspace layout (float offsets) ----------------
static const size_t OFF_CONV3  = 0;              // [8192][1568] f32 (phase 1)
static const size_t OFF_MWFHI  = 0;              // [4096*1024] bf16  (phase 2)
static const size_t OFF_MWFLO  = 2097152;        // [4096*1024] bf16
static const size_t OFF_EWFHI  = 4194304;        // [1024*256] bf16
static const size_t OFF_EWFLO  = 4325376;        // [1024*256] bf16
static const size_t OFF_HBMHI  = 4456448;        // [2][128][1024] bf16
static const size_t OFF_HBMLO  = 4587520;        // [2][128][1024] bf16
static const size_t OFF_HBEHI  = 4718592;        // [2][128][256] bf16
static const size_t OFF_HBELO  = 4734976;        // [2][128][256] bf16
static const size_t OFF_CBM    = 4767744;        // [128][1024] f32 (mem c state)
static const size_t OFF_CBE    = 4898816;        // [128][256] f32 (enc c state)
static const size_t OFF_IMGH   = 12845056;       // [8192][256]
static const size_t OFF_LANGIN = 14942208;       // [8192][32]
static const size_t OFF_ENCXW  = 15204352;       // [8192][1024]
static const size_t OFF_ENCHS  = 23592960;       // [8192][256]
static const size_t OFF_LANGH  = 25690112;       // [8192][32]
static const size_t OFF_HIDDEN = 25952256;       // [8192][288]
static const size_t OFF_MEMXW  = 28311552;       // [8192][4096]
static const size_t OFF_MEMHS  = 61865984;       // [8192][1024]
static const size_t OFF_ENCBC  = 70582272;       // [1024]
static const size_t OFF_MEMBC  = 70583296;       // [4096]
static const size_t OFF_HEADW  = 70587392;       // [16][1024]
static const size_t OFF_HEADB  = 70603776;       // [16]

__device__ __forceinline__ float fast_sigm(float x) { return 1.0f / (1.0f + __expf(-x)); }
__device__ __forceinline__ float fast_tanh(float x) { return 2.0f / (1.0f + __expf(-2.0f * x)) - 1.0f; }

__device__ __forceinline__ short f32_to_bf16_rne(float x) {
    unsigned u = __float_as_uint(x);
    unsigned r = (u + 0x7fffu + ((u >> 16) & 1u)) >> 16;
    return (short)r;
}
__device__ __forceinline__ float bf16s_to_f32(short s) {
    return __uint_as_float(((unsigned)(unsigned short)s) << 16);
}

// ---------------- prep ----------------
__global__ void prep_kernel(const float* __restrict__ enc_bih, const float* __restrict__ enc_bhh,
                            const float* __restrict__ mem_bih, const float* __restrict__ mem_bhh,
                            const float* __restrict__ actor_w, const float* __restrict__ actor_b,
                            const float* __restrict__ critic_w, const float* __restrict__ critic_b,
                            float* __restrict__ enc_bc, float* __restrict__ mem_bc,
                            float* __restrict__ head_w, float* __restrict__ head_b) {
    int g = blockIdx.x * 256 + threadIdx.x;
    if (g < 1024)  enc_bc[g] = enc_bih[g] + enc_bhh[g];
    if (g < 4096)  mem_bc[g] = mem_bih[g] + mem_bhh[g];
    if (g < 16384) { int j = g >> 10, k = g & 1023; head_w[g] = (j < 15) ? actor_w[j * 1024 + k] : critic_w[k]; }
    if (g < 16)    head_b[g] = (g < 15) ? actor_b[g] : critic_b[0];
}

// ---------------- init LSTM state: split h0 into hi/lo, copy c0 ----------------
__global__ void init_state_kernel(const float* __restrict__ h0, const float* __restrict__ c0,
                                  short* __restrict__ hhi, short* __restrict__ hlo,
                                  float* __restrict__ cb, int n) {
    int g = blockIdx.x * 256 + threadIdx.x;
    if (g < n) {
        float v = h0[g];
        short a = f32_to_bf16_rne(v);
        hhi[g] = a;
        hlo[g] = f32_to_bf16_rne(v - bf16s_to_f32(a));
        cb[g] = c0[g];
    }
}

// ---------------- split Whh into MFMA-fragment-ordered bf16 hi/lo ----------------
__global__ void split_frag_kernel(const float* __restrict__ W, short* __restrict__ hi,
                                  short* __restrict__ lo, int H) {
    size_t f = (size_t)blockIdx.x * 256 + threadIdx.x;
    size_t total = (size_t)4 * H * H;
    if (f >= total) return;
    int e    = (int)(f & 7);
    int lane = (int)((f >> 3) & 63);
    size_t rest = f >> 9;
    int nks = H >> 5;
    int ks  = (int)(rest % nks);
    int qjt = (int)(rest / nks);
    int njt = H >> 4;
    int qq = qjt / njt, jt = qjt - qq * njt;
    int n = qq * H + jt * 16 + (lane & 15);
    int k = ks * 32 + (lane >> 4) * 8 + e;
    float w = W[(size_t)n * H + k];
    short a = f32_to_bf16_rne(w);
    short b = f32_to_bf16_rne(w - bf16s_to_f32(a));
    hi[f] = a; lo[f] = b;
}

// ---------------- fused conv stack, one block per image ----------------
__global__ __launch_bounds__(256) void conv_kernel(const float* __restrict__ x,
        const float* __restrict__ w1, const float* __restrict__ b1,
        const float* __restrict__ w2, const float* __restrict__ b2,
        const float* __restrict__ w3, const float* __restrict__ b3,
        float* __restrict__ out) {
    __shared__ float arena[16384];
    const int t = threadIdx.x;
    const size_t img = blockIdx.x;

    float* s_out1 = arena;
    float* s_w1   = arena + 1936;
    float* s_b1   = arena + 3232;
    float* s_img  = arena + 3248;
    const float* xi = x + img * 9801;
    for (int i = t; i < 9801; i += 256) s_img[i] = xi[i] * (1.0f / 255.0f);
    for (int i = t; i < 1296; i += 256) s_w1[i] = w1[i];
    if (t < 16) s_b1[t] = b1[t];
    __syncthreads();

    if (t < 176) {
        int c = t / 11, i = t - c * 11;
        float accr[11];
        #pragma unroll
        for (int j = 0; j < 11; ++j) accr[j] = s_b1[c];
        for (int ky = 0; ky < 9; ++ky) {
            const float* irow = s_img + (i * 9 + ky) * 99;
            const float* wrow = s_w1 + c * 81 + ky * 9;
            for (int kx = 0; kx < 9; ++kx) {
                float wv = wrow[kx];
                #pragma unroll
                for (int j = 0; j < 11; ++j) accr[j] += wv * irow[j * 9 + kx];
            }
        }
        #pragma unroll
        for (int j = 0; j < 11; ++j) s_out1[c * 121 + i * 11 + j] = fmaxf(accr[j], 0.0f);
    }
    __syncthreads();

    float* s_w2   = arena + 1936;
    float* s_b2   = arena + 6544;
    float* s_out2 = arena + 13792;
    for (int i = t; i < 4608; i += 256) s_w2[i] = w2[i];
    if (t < 32) s_b2[t] = b2[t];
    __syncthreads();

    for (int rr = 0; rr < 2; ++rr) {
        int task = rr * 256 + t;
        if (task < 288) {
            int c = task / 9, i = task - c * 9;
            float accr[9];
            #pragma unroll
            for (int j = 0; j < 9; ++j) accr[j] = s_b2[c];
            for (int ic = 0; ic < 16; ++ic) {
                const float* ibase = s_out1 + ic * 121 + i * 11;
                const float* wbase = s_w2 + (c * 16 + ic) * 9;
                #pragma unroll
                for (int ky = 0; ky < 3; ++ky) {
                    const float* irow = ibase + ky * 11;
                    #pragma unroll
                    for (int kx = 0; kx < 3; ++kx) {
                        float wv = wbase[ky * 3 + kx];
                        #pragma unroll
                        for (int j = 0; j < 9; ++j) accr[j] += wv * irow[j + kx];
                    }
                }
            }
            #pragma unroll
            for (int j = 0; j < 9; ++j) s_out2[c * 81 + i * 9 + j] = fmaxf(accr[j], 0.0f);
        }
    }
    __syncthreads();

    float* s_w3   = arena;
    float* s_b3   = arena + 9216;
    float* s_out3 = arena + 9248;
    for (int i = t; i < 9216; i += 256) s_w3[i] = w3[i];
    if (t < 32) s_b3[t] = b3[t];
    __syncthreads();

    if (t < 224) {
        int c = t / 7, i = t - c * 7;
        float accr[7];
        #pragma unroll
        for (int j = 0; j < 7; ++j) accr[j] = s_b3[c];
        for (int ic = 0; ic < 32; ++ic) {
            const float* ibase = s_out2 + ic * 81 + i * 9;
            const float* wbase = s_w3 + (c * 32 + ic) * 9;
            #pragma unroll
            for (int ky = 0; ky < 3; ++ky) {
                const float* irow = ibase + ky * 9;
                #pragma unroll
                for (int kx = 0; kx < 3; ++kx) {
                    float wv = wbase[ky * 3 + kx];
                    #pragma unroll
                    for (int j = 0; j < 7; ++j) accr[j] += wv * irow[j + kx];
                }
            }
        }
        #pragma unroll
        for (int j = 0; j < 7; ++j) s_out3[c * 49 + i * 7 + j] = fmaxf(accr[j], 0.0f);
    }
    __syncthreads();
    float* og = out + img * 1568;
    for (int i = t; i < 1568; i += 256) og[i] = s_out3[i];
}

// ---------------- generic tiled GEMM ----------------
template <bool RELU>
__global__ __launch_bounds__(64) void gemm64(const float* __restrict__ A, const float* __restrict__ W,
                                             const float* __restrict__ bias, float* __restrict__ C,
                                             int M, int N, int K) {
    __shared__ float At[32][68];
    __shared__ float Wt[32][68];
    const int m0 = blockIdx.x * 64, n0 = blockIdx.y * 64;
    const int t = threadIdx.x;
    const int tx = t & 7, ty = t >> 3;
    float acc[8][8] = {};
    for (int kc = 0; kc < K; kc += 32) {
        #pragma unroll
        for (int i = 0; i < 8; ++i) {
            int e = t + i * 64;
            int row = e >> 3, c4 = (e & 7) * 4;
            float4 v = *(const float4*)&A[(size_t)(m0 + row) * K + kc + c4];
            At[c4 + 0][row] = v.x; At[c4 + 1][row] = v.y; At[c4 + 2][row] = v.z; At[c4 + 3][row] = v.w;
            int n = n0 + row;
            float4 wv = make_float4(0.f, 0.f, 0.f, 0.f);
            if (n < N) wv = *(const float4*)&W[(size_t)n * K + kc + c4];
            Wt[c4 + 0][row] = wv.x; Wt[c4 + 1][row] = wv.y; Wt[c4 + 2][row] = wv.z; Wt[c4 + 3][row] = wv.w;
        }
        __syncthreads();
        #pragma unroll
        for (int kk = 0; kk < 32; ++kk) {
            float4 a0 = *(const float4*)&At[kk][ty * 8];
            float4 a1 = *(const float4*)&At[kk][ty * 8 + 4];
            float4 b0 = *(const float4*)&Wt[kk][tx * 8];
            float4 b1 = *(const float4*)&Wt[kk][tx * 8 + 4];
            float a[8] = {a0.x, a0.y, a0.z, a0.w, a1.x, a1.y, a1.z, a1.w};
            float b[8] = {b0.x, b0.y, b0.z, b0.w, b1.x, b1.y, b1.z, b1.w};
            #pragma unroll
            for (int i = 0; i < 8; ++i)
                #pragma unroll
                for (int j = 0; j < 8; ++j) acc[i][j] += a[i] * b[j];
        }
        __syncthreads();
    }
    #pragma unroll
    for (int i = 0; i < 8; ++i) {
        int m = m0 + ty * 8 + i;
        #pragma unroll
        for (int j = 0; j < 8; ++j) {
            int n = n0 + tx * 8 + j;
            if (n < N) {
                float v = acc[i][j] + bias[n];
                if (RELU) v = fmaxf(v, 0.0f);
                C[(size_t)m * N + n] = v;
            }
        }
    }
}

// ---------------- embedding ----------------
__global__ void embed_kernel(const int* __restrict__ lang, const float* __restrict__ emb,
                             float* __restrict__ out) {
    int g = blockIdx.x * 256 + threadIdx.x;
    if (g < TBTOT * 32) { int r = g >> 5, c = g & 31; out[g] = emb[lang[r] * 32 + c]; }
}

// ---------------- concat ----------------
__global__ void concat_kernel(const float* __restrict__ img_h, const float* __restrict__ lang_h,
                              float* __restrict__ out) {
    int r = blockIdx.x, c = threadIdx.x;
    out[r * 288 + c] = (c < 256) ? img_h[r * 256 + c] : lang_h[r * 32 + (c - 256)];
}

// ---------------- ONE LSTM STEP as its own kernel (no persistent scan, no barrier) ----------------
// Kernel boundary = device-wide sync + cross-XCD visibility (hardware-managed).
// grid (H/16, 4), 256 threads = 4 waves, wave q computes gate q for 32x16 tile.
// h ping-pongs between h_src/h_dst (swapped pointers per launch); c state in cbuf.
template <int H, bool PER_ENV>
__global__ __launch_bounds__(256) void lstm_step_kernel(
        const float* __restrict__ xw_s,    // [B][4H] for this step
        const short* __restrict__ wf_hi,
        const short* __restrict__ wf_lo,
        const float* __restrict__ done_s,  // PER_ENV ? [B] for this step : [1] scalar
        const short* __restrict__ hs_hi, const short* __restrict__ hs_lo,  // h(t) split
        short* __restrict__ hd_hi, short* __restrict__ hd_lo,              // h(t+1) split
        float* __restrict__ cbuf,          // [B][H] f32 c state
        float* __restrict__ hs_out) {      // [B][H] f32 output h for this step
    __shared__ bf16x8 lsA[2][1024];
    __shared__ float  gbuf[4][32][16];
    const int t    = threadIdx.x;
    const int lane = t & 63;
    const int q    = t >> 6;
    const int jt   = blockIdx.x;
    const int j0   = jt * 16;
    const int b0   = blockIdx.y * 32;
    const int jl   = t & 15, bl = (t >> 4) & 15;
    const int jg   = j0 + jl;
    const int njt  = H >> 4, nks = H >> 5;

    const float m_step = PER_ENV ? 0.0f : (1.0f - done_s[0]);

    // xw gate biases + masks for this thread's two cells
    float xg[2][4], m_e[2];
    #pragma unroll
    for (int e = 0; e < 2; ++e) {
        int bgl = b0 + bl + e * 16;
        const float* xr = xw_s + (size_t)bgl * (4 * H);
        #pragma unroll
        for (int g4 = 0; g4 < 4; ++g4) xg[e][g4] = xr[g4 * H + jg];
        m_e[e] = PER_ENV ? (1.0f - done_s[bgl]) : m_step;
    }

    f32x4 acc0 = {0.f, 0.f, 0.f, 0.f};
    f32x4 acc1 = {0.f, 0.f, 0.f, 0.f};
    const bf16x8* bfh = (const bf16x8*)wf_hi + (size_t)(q * njt + jt) * nks * 64;
    const bf16x8* bfl = (const bf16x8*)wf_lo + (size_t)(q * njt + jt) * nks * 64;
    const bf16x8 zero8 = {0, 0, 0, 0, 0, 0, 0, 0};

    for (int cch = 0; cch < H / 256; ++cch) {
        const int k0 = cch * 256;
        #pragma unroll
        for (int i = 0; i < 4; ++i) {
            int idx = i * 256 + t;
            int row = idx >> 5, seg = idx & 31;
            float m = PER_ENV ? (1.0f - done_s[b0 + row]) : m_step;
            int slot = seg * 32 + ((row ^ seg) & 31);
            bf16x8 vh = *(const bf16x8*)&hs_hi[(size_t)(b0 + row) * H + k0 + seg * 8];
            bf16x8 vl = *(const bf16x8*)&hs_lo[(size_t)(b0 + row) * H + k0 + seg * 8];
            if (m == 0.0f) { vh = zero8; vl = zero8; }
            lsA[0][slot] = vh;
            lsA[1][slot] = vl;
        }
        __syncthreads();
        #pragma unroll
        for (int ksl = 0; ksl < 8; ++ksl) {
            int ks = (k0 >> 5) + ksl;
            bf16x8 b_hi = bfh[(size_t)ks * 64 + lane];
            bf16x8 b_lo = bfl[(size_t)ks * 64 + lane];
            int kgrp = ksl * 4 + (lane >> 4);
            int r0 = lane & 15, r1 = r0 + 16;
            bf16x8 a0h = lsA[0][kgrp * 32 + ((r0 ^ kgrp) & 31)];
            bf16x8 a0l = lsA[1][kgrp * 32 + ((r0 ^ kgrp) & 31)];
            bf16x8 a1h = lsA[0][kgrp * 32 + ((r1 ^ kgrp) & 31)];
            bf16x8 a1l = lsA[1][kgrp * 32 + ((r1 ^ kgrp) & 31)];
            acc0 = __builtin_amdgcn_mfma_f32_16x16x32_bf16(a0h, b_hi, acc0, 0, 0, 0);
            acc1 = __builtin_amdgcn_mfma_f32_16x16x32_bf16(a1h, b_hi, acc1, 0, 0, 0);
            acc0 = __builtin_amdgcn_mfma_f32_16x16x32_bf16(a0h, b_lo, acc0, 0, 0, 0);
            acc1 = __builtin_amdgcn_mfma_f32_16x16x32_bf16(a1h, b_lo, acc1, 0, 0, 0);
            acc0 = __builtin_amdgcn_mfma_f32_16x16x32_bf16(a0l, b_hi, acc0, 0, 0, 0);
            acc1 = __builtin_amdgcn_mfma_f32_16x16x32_bf16(a1l, b_hi, acc1, 0, 0, 0);
        }
        __syncthreads();
    }

    // cross-wave gate exchange (C/D layout: col=lane&15, row=(lane>>4)*4+r)
    #pragma unroll
    for (int r = 0; r < 4; ++r) {
        gbuf[q][(lane >> 4) * 4 + r][lane & 15]      = acc0[r];
        gbuf[q][16 + (lane >> 4) * 4 + r][lane & 15] = acc1[r];
    }
    __syncthreads();

    #pragma unroll
    for (int e = 0; e < 2; ++e) {
        int b_loc = bl + e * 16;
        int bgl = b0 + b_loc;
        float m = m_e[e];
        float gi = gbuf[0][b_loc][jl] + xg[e][0];
        float gf = gbuf[1][b_loc][jl] + xg[e][1];
        float gg = gbuf[2][b_loc][jl] + xg[e][2];
        float go = gbuf[3][b_loc][jl] + xg[e][3];
        size_t ci = (size_t)bgl * H + jg;
        float cc = fast_sigm(gf) * (cbuf[ci] * m) + fast_sigm(gi) * fast_tanh(gg);
        float hh = fast_sigm(go) * fast_tanh(cc);
        cbuf[ci] = cc;
        hs_out[ci] = hh;
        short hhi = f32_to_bf16_rne(hh);
        short hlo = f32_to_bf16_rne(hh - bf16s_to_f32(hhi));
        hd_hi[ci] = hhi;
        hd_lo[ci] = hlo;
    }
}

extern "C" void kernel_launch(void* const* d_in, const int* in_sizes, int n_in,
                              void* d_out, int out_size, void* d_ws, size_t ws_size,
                              hipStream_t stream) {
    const float* x_img    = (const float*)d_in[0];
    const int*   x_lang   = (const int*)d_in[1];
    const float* done     = (const float*)d_in[2];
    const float* enc_h0   = (const float*)d_in[3];
    const float* enc_c0   = (const float*)d_in[4];
    const float* mem_h0   = (const float*)d_in[5];
    const float* mem_c0   = (const float*)d_in[6];
    const float* emb      = (const float*)d_in[7];
    const float* conv1_w  = (const float*)d_in[8];
    const float* conv1_b  = (const float*)d_in[9];
    const float* conv2_w  = (const float*)d_in[10];
    const float* conv2_b  = (const float*)d_in[11];
    const float* conv3_w  = (const float*)d_in[12];
    const float* conv3_b  = (const float*)d_in[13];
    const float* fc_w     = (const float*)d_in[14];
    const float* fc_b     = (const float*)d_in[15];
    const float* enc_Wih  = (const float*)d_in[16];
    const float* enc_Whh  = (const float*)d_in[17];
    const float* enc_bih  = (const float*)d_in[18];
    const float* enc_bhh  = (const float*)d_in[19];
    const float* lemb_w   = (const float*)d_in[20];
    const float* lemb_b   = (const float*)d_in[21];
    const float* mem_Wih  = (const float*)d_in[22];
    const float* mem_Whh  = (const float*)d_in[23];
    const float* mem_bih  = (const float*)d_in[24];
    const float* mem_bhh  = (const float*)d_in[25];
    const float* actor_w  = (const float*)d_in[26];
    const float* actor_b  = (const float*)d_in[27];
    const float* critic_w = (const float*)d_in[28];
    const float* critic_b = (const float*)d_in[29];

    float* ws = (float*)d_ws;
    float* conv3_flat = ws + OFF_CONV3;
    short* mem_wf_hi  = (short*)(ws + OFF_MWFHI);
    short* mem_wf_lo  = (short*)(ws + OFF_MWFLO);
    short* enc_wf_hi  = (short*)(ws + OFF_EWFHI);
    short* enc_wf_lo  = (short*)(ws + OFF_EWFLO);
    short* hbm_hi     = (short*)(ws + OFF_HBMHI);
    short* hbm_lo     = (short*)(ws + OFF_HBMLO);
    short* hbe_hi     = (short*)(ws + OFF_HBEHI);
    short* hbe_lo     = (short*)(ws + OFF_HBELO);
    float* cbm        = ws + OFF_CBM;
    float* cbe        = ws + OFF_CBE;
    float* img_hidden = ws + OFF_IMGH;
    float* lang_in    = ws + OFF_LANGIN;
    float* enc_xW     = ws + OFF_ENCXW;
    float* enc_hs     = ws + OFF_ENCHS;
    float* lang_h     = ws + OFF_LANGH;
    float* hidden     = ws + OFF_HIDDEN;
    float* mem_xW     = ws + OFF_MEMXW;
    float* mem_hs     = ws + OFF_MEMHS;
    float* enc_bc     = ws + OFF_ENCBC;
    float* mem_bc     = ws + OFF_MEMBC;
    float* head_w     = ws + OFF_HEADW;
    float* head_b     = ws + OFF_HEADB;

    prep_kernel<<<64, 256, 0, stream>>>(enc_bih, enc_bhh, mem_bih, mem_bhh,
                                        actor_w, actor_b, critic_w, critic_b,
                                        enc_bc, mem_bc, head_w, head_b);
    conv_kernel<<<TBTOT, 256, 0, stream>>>(x_img, conv1_w, conv1_b, conv2_w, conv2_b,
                                           conv3_w, conv3_b, conv3_flat);
    gemm64<true><<<dim3(128, 4), 64, 0, stream>>>(conv3_flat, fc_w, fc_b, img_hidden, TBTOT, 256, 1568);
    // conv3 region dead from here; build LSTM split-weight fragments + state in it
    split_frag_kernel<<<65536, 256, 0, stream>>>(mem_Whh, mem_wf_hi, mem_wf_lo, 1024);
    split_frag_kernel<<<4096, 256, 0, stream>>>(enc_Whh, enc_wf_hi, enc_wf_lo, 256);
    init_state_kernel<<<128, 256, 0, stream>>>(enc_h0, enc_c0, hbe_hi, hbe_lo, cbe, BATCH * 256);
    init_state_kernel<<<512, 256, 0, stream>>>(mem_h0, mem_c0, hbm_hi, hbm_lo, cbm, BATCH * 1024);
    embed_kernel<<<1024, 256, 0, stream>>>(x_lang, emb, lang_in);
    gemm64<false><<<dim3(128, 16), 64, 0, stream>>>(lang_in, enc_Wih, enc_bc, enc_xW, TBTOT, 1024, 32);

    // ---- encoder scan: 64 per-step kernels ----
    {
        int cur = 0;
        for (int st = 0; st < T_STEPS; ++st) {
            lstm_step_kernel<256, false><<<dim3(16, 4), 256, 0, stream>>>(
                enc_xW + (size_t)st * BATCH * 1024, enc_wf_hi, enc_wf_lo, done + st,
                hbe_hi + (size_t)cur * (BATCH * 256), hbe_lo + (size_t)cur * (BATCH * 256),
                hbe_hi + (size_t)(cur ^ 1) * (BATCH * 256), hbe_lo + (size_t)(cur ^ 1) * (BATCH * 256),
                cbe, enc_hs + (size_t)st * BATCH * 256);
            cur ^= 1;
        }
    }
    gemm64<true><<<dim3(128, 1), 64, 0, stream>>>(enc_hs, lemb_w, lemb_b, lang_h, TBTOT, 32, 256);
    concat_kernel<<<TBTOT, 288, 0, stream>>>(img_hidden, lang_h, hidden);
    gemm64<false><<<dim3(128, 64), 64, 0, stream>>>(hidden, mem_Wih, mem_bc, mem_xW, TBTOT, 4096, 288);

    // ---- memory scan: 64 per-step kernels ----
    {
        int cur = 0;
        for (int st = 0; st < T_STEPS; ++st) {
            lstm_step_kernel<1024, true><<<dim3(64, 4), 256, 0, stream>>>(
                mem_xW + (size_t)st * BATCH * 4096, mem_wf_hi, mem_wf_lo, done + (size_t)st * BATCH,
                hbm_hi + (size_t)cur * (BATCH * 1024), hbm_lo + (size_t)cur * (BATCH * 1024),
                hbm_hi + (size_t)(cur ^ 1) * (BATCH * 1024), hbm_lo + (size_t)(cur ^ 1) * (BATCH * 1024),
                cbm, mem_hs + (size_t)st * BATCH * 1024);
            cur ^= 1;
        }
    }
    gemm64<false><<<dim3(128, 1), 64, 0, stream>>>(mem_hs, head_w, head_b, (float*)d_out, TBTOT, 16, 1024);
}